// Round 3
// baseline (275.901 us; speedup 1.0000x reference)
//
#include <hip/hip_runtime.h>
#include <hip/hip_bf16.h>
#include <hip/hip_fp16.h>
#include <math.h>

// B=8, H=16, N=1024, D=1024, hd=64
// ws layout (float units):
//   qpre f16 (B,H,N,64)   [0, 4M)        8M halfs   (normed+roped by gemm)
//   kpre f16 (B,H,N,64)   [4M, 8M)
//   vT   f16 (B,H,64,N)   [8M, 12M)      transposed per head
//   xb   bf16 [12M,16M)   (reused as ob after QKV gemm)
//   wqT  bf16 [16M,17.5M) ; woT bf16 [17.5M,18M)
// total 72 MB
#define QSZ 8388608  // halfs per q/k/v region

typedef short bf16x8 __attribute__((ext_vector_type(8)));
typedef _Float16 f16x8 __attribute__((ext_vector_type(8)));
typedef float f32x4 __attribute__((ext_vector_type(4)));

__device__ __forceinline__ unsigned short f2bf(float f) {
  __hip_bfloat16 h = __float2bfloat16(f);
  return *reinterpret_cast<unsigned short*>(&h);
}

__device__ __forceinline__ void gload16(const void* g, void* l) {
  __builtin_amdgcn_global_load_lds(
      (const __attribute__((address_space(1))) void*)g,
      (__attribute__((address_space(3))) void*)l, 16, 0, 0);
}

// ---------------------------------------------------------------------------
__global__ __launch_bounds__(256)
void cvt_bf16(const float* __restrict__ src, unsigned short* __restrict__ dst) {
  const int i = (blockIdx.x * 256 + threadIdx.x) * 8;
  const float4 a = *(const float4*)&src[i];
  const float4 b = *(const float4*)&src[i + 4];
  ushort4 lo, hi;
  lo.x = f2bf(a.x); lo.y = f2bf(a.y); lo.z = f2bf(a.z); lo.w = f2bf(a.w);
  hi.x = f2bf(b.x); hi.y = f2bf(b.y); hi.z = f2bf(b.z); hi.w = f2bf(b.w);
  *(ushort4*)&dst[i] = lo;
  *(ushort4*)&dst[i + 4] = hi;
}

// transpose+convert: src [1024,N] fp32 -> dst [N,1024] bf16
__global__ __launch_bounds__(256)
void cvt_t(const float* __restrict__ src, unsigned short* __restrict__ dst,
           const int N) {
  __shared__ unsigned short tile[32][33];
  const int k0 = blockIdx.y * 32, n0 = blockIdx.x * 32;
  const int t = threadIdx.x;
  const int r = t >> 3, c4 = (t & 7) * 4;
  const float4 v = *(const float4*)&src[(k0 + r) * N + n0 + c4];
  tile[r][c4 + 0] = f2bf(v.x);
  tile[r][c4 + 1] = f2bf(v.y);
  tile[r][c4 + 2] = f2bf(v.z);
  tile[r][c4 + 3] = f2bf(v.w);
  __syncthreads();
  ushort4 o;
  o.x = tile[c4 + 0][r];
  o.y = tile[c4 + 1][r];
  o.z = tile[c4 + 2][r];
  o.w = tile[c4 + 3][r];
  *(ushort4*)&dst[(long)(n0 + r) * 1024 + k0 + c4] = o;
}

// ---------------------------------------------------------------------------
// QKV projection: 256x256-tile bf16 GEMM, 4-phase counted-vmcnt pipeline.
// LDS = 4-slot ring of kk-half tiles (256 rows x 32 cols, A+B), 2-bit XOR
// swizzle (chunk ^= row&3) applied as inverse-swizzled global source +
// swizzled ds_read. Per K-tile: 4 phases, each {8/4 ds_read_b128 + 2
// gload_lds issue -> s_barrier -> lgkmcnt(0) -> setprio(1) 16xMFMA
// setprio(0) -> [vmcnt(8) at ph1/ph3] -> s_barrier}. Loads never drain
// below 8 in the main loop (3 half-tiles in flight).
// Ring safety: G=2t+3's slot last read in tile t-1 ph3 (barrier-separated);
// G=2t+4's slot (=h0) freed by end-of-ph1 barrier before its ph2 stage.
// q is pre-scaled by hd^-0.5 * log2(e) so attention softmax is a bare exp2.
// ---------------------------------------------------------------------------
__global__ __launch_bounds__(512, 2)
void gemm_qkv(const unsigned short* __restrict__ A,
              const unsigned short* __restrict__ Bt,
              const float* __restrict__ bias,
              __half* __restrict__ Ch,
              const float* __restrict__ qsc,
              const float* __restrict__ ksc) {
  __shared__ __align__(16) unsigned short HA[4][8192];  // 4 half-slots A
  __shared__ __align__(16) unsigned short HB[4][8192];  // 4 half-slots B
  __shared__ float2 Tab[512];  // [pos 0..31][idx 0..15] cos/sin

  const int t = threadIdx.x;
  // bijective XCD swizzle (384 % 8 == 0): XCD x owns bm in [4x, 4x+4)
  const int swz = (blockIdx.x & 7) * 48 + (blockIdx.x >> 3);
  const int bm = swz / 12, bn = swz % 12;
  const int w = t >> 6, lane = t & 63;
  const int M0 = (w >> 2) * 128, N0 = (w & 3) * 64;
  const int lm = lane & 15, q4 = lane >> 4;

  {  // RoPE table: one entry per thread (ds_write retires at first lgkmcnt)
    const int pos = t >> 4, idx = t & 15;
    const float invf = expf(-(float)idx * 0.57564627324851149f);
    const float ang = (float)pos * invf;
    Tab[t] = make_float2(cosf(ang), sinf(ang));
  }

  // staging: thread t covers row (t>>2)+128j, physical chunk t&3 (lane-linear
  // LDS dest = t*16B); inverse-swizzled global source chunk = (t&3)^(row&3).
  const int c8 = (((t & 3) ^ ((t >> 2) & 3)) << 3);
  const unsigned short* aSrc = A + (long)(bm * 256 + (t >> 2)) * 1024 + c8;
  const unsigned short* bSrc = Bt + (long)(bn * 256 + (t >> 2)) * 1024 + c8;

  f32x4 acc[8][4] = {};

  auto stageA = [&](int G) {  // half-tile G of A: 2 gload_lds per thread
    const unsigned short* a = aSrc + ((G >> 1) << 6) + ((G & 1) << 5);
    unsigned short* la = &HA[G & 3][t * 8];
    gload16(a, la);
    gload16(a + 128 * 1024, la + 4096);
  };
  auto stageB = [&](int G) {
    const unsigned short* b = bSrc + ((G >> 1) << 6) + ((G & 1) << 5);
    unsigned short* lb = &HB[G & 3][t * 8];
    gload16(b, lb);
    gload16(b + 128 * 1024, lb + 4096);
  };

  auto rdA4 = [&](bf16x8* dst, int slot, int mi0) {
#pragma unroll
    for (int i = 0; i < 4; ++i) {
      const int r = M0 + (mi0 + i) * 16 + lm;
      dst[i] = *(const bf16x8*)&HA[slot][r * 32 + ((q4 ^ (lm & 3)) << 3)];
    }
  };
  auto rdB4 = [&](bf16x8* dst, int slot) {
#pragma unroll
    for (int i = 0; i < 4; ++i) {
      const int r = N0 + i * 16 + lm;
      dst[i] = *(const bf16x8*)&HB[slot][r * 32 + ((q4 ^ (lm & 3)) << 3)];
    }
  };
  auto mfmaQ = [&](const bf16x8* fa, const bf16x8* fb, int mb) {
    __builtin_amdgcn_s_setprio(1);
#pragma unroll
    for (int mi = 0; mi < 4; ++mi)
#pragma unroll
      for (int ni = 0; ni < 4; ++ni)
        acc[mb + mi][ni] = __builtin_amdgcn_mfma_f32_16x16x32_bf16(
            fa[mi], fb[ni], acc[mb + mi][ni], 0, 0, 0);
    __builtin_amdgcn_s_setprio(0);
  };
  auto bar = [] { __builtin_amdgcn_s_barrier(); };
  auto lgkm0 = [] {
    asm volatile("s_waitcnt lgkmcnt(0)" ::: "memory");
    __builtin_amdgcn_sched_barrier(0);
  };

  // prologue: halves G0,G1,G2 in flight (12 loads); wait G0 (12 -> 8)
  stageA(0); stageB(0);
  stageA(1); stageB(1);
  stageA(2); stageB(2);
  asm volatile("s_waitcnt vmcnt(8)" ::: "memory");
  bar();

  bf16x8 fa[4], fb[4], fa2[4];
  for (int kt = 0; kt < 14; ++kt) {
    const int h0 = (2 * kt) & 3, h1 = (2 * kt + 1) & 3;
    // ph0: kk0, mi 0-3
    rdA4(fa, h0, 0); rdB4(fb, h0);
    stageA(2 * kt + 3);
    bar(); lgkm0(); mfmaQ(fa, fb, 0); bar();
    // ph1: kk0, mi 4-7
    rdA4(fa2, h0, 4);
    stageB(2 * kt + 3);
    bar(); lgkm0(); mfmaQ(fa2, fb, 4);
    asm volatile("s_waitcnt vmcnt(8)" ::: "memory");  // retire G=2kt+1
    bar();
    // ph2: kk1, mi 0-3
    rdA4(fa, h1, 0); rdB4(fb, h1);
    stageA(2 * kt + 4);
    bar(); lgkm0(); mfmaQ(fa, fb, 0); bar();
    // ph3: kk1, mi 4-7
    rdA4(fa2, h1, 4);
    stageB(2 * kt + 4);
    bar(); lgkm0(); mfmaQ(fa2, fb, 4);
    asm volatile("s_waitcnt vmcnt(8)" ::: "memory");  // retire G=2kt+2
    bar();
  }
  {  // kt = 14: stage G31 only; end-ph3 wait vmcnt(4) (retire G30)
    rdA4(fa, 0, 0); rdB4(fb, 0);
    stageA(31);
    bar(); lgkm0(); mfmaQ(fa, fb, 0); bar();
    rdA4(fa2, 0, 4);
    stageB(31);
    bar(); lgkm0(); mfmaQ(fa2, fb, 4);
    asm volatile("s_waitcnt vmcnt(8)" ::: "memory");  // retire G29
    bar();
    rdA4(fa, 1, 0); rdB4(fb, 1);
    bar(); lgkm0(); mfmaQ(fa, fb, 0); bar();
    rdA4(fa2, 1, 4);
    bar(); lgkm0(); mfmaQ(fa2, fb, 4);
    asm volatile("s_waitcnt vmcnt(4)" ::: "memory");  // retire G30
    bar();
  }
  {  // kt = 15: no staging; end-ph1 wait vmcnt(0) (retire G31)
    rdA4(fa, 2, 0); rdB4(fb, 2);
    bar(); lgkm0(); mfmaQ(fa, fb, 0); bar();
    rdA4(fa2, 2, 4);
    bar(); lgkm0(); mfmaQ(fa2, fb, 4);
    asm volatile("s_waitcnt vmcnt(0)" ::: "memory");  // retire G31
    bar();
    rdA4(fa, 3, 0); rdB4(fb, 3);
    bar(); lgkm0(); mfmaQ(fa, fb, 0); bar();
    rdA4(fa2, 3, 4);
    bar(); lgkm0(); mfmaQ(fa2, fb, 4);
  }

  // ---- fused epilogue (wave col-span = one head) ----
  const int r0 = q4 << 2;
  const int nb = bn * 256 + N0;
  const int tq = nb >> 10, h = (nb >> 6) & 15;

  if (tq == 2) {  // v: f16 transpose-scatter (B,H,64,N)
#pragma unroll
    for (int mi = 0; mi < 8; ++mi)
#pragma unroll
      for (int ni = 0; ni < 4; ++ni) {
        const int col = nb + ni * 16 + lm;
        const int dd = col & 63;
        const float bv = bias[col];
#pragma unroll
        for (int r = 0; r < 4; ++r) {
          const int m = bm * 256 + M0 + mi * 16 + r0 + r;
          const int b = m >> 10, nn = m & 1023;
          Ch[2L * QSZ + ((long)((b * 16 + h) * 64 + dd)) * 1024 + nn] =
              __float2half(acc[mi][ni][r] + bv);
        }
      }
    return;
  }

  // q or k: RMSNorm + RoPE on f32 accs, then f16 store (B,H,N,64)
  const float* scp = (tq == 0) ? qsc : ksc;
  // q: fold hd^-0.5 AND log2(e) (softmax uses exp2) into the stored q
  const float qmul = (tq == 0) ? 0.18033688011112042f : 1.0f;
  float scv[4], bv[4];
#pragma unroll
  for (int ni = 0; ni < 4; ++ni) {
    scv[ni] = scp[ni * 16 + lm];
    bv[ni] = bias[nb + ni * 16 + lm];
  }
  __half* base = Ch + (long)tq * QSZ;
#pragma unroll
  for (int mi = 0; mi < 8; ++mi) {
#pragma unroll
    for (int r = 0; r < 4; ++r) {
      const float v0 = acc[mi][0][r] + bv[0];
      const float v1 = acc[mi][1][r] + bv[1];
      const float v2 = acc[mi][2][r] + bv[2];
      const float v3 = acc[mi][3][r] + bv[3];
      float ss = v0 * v0 + v1 * v1 + v2 * v2 + v3 * v3;
      ss += __shfl_xor(ss, 1, 64);
      ss += __shfl_xor(ss, 2, 64);
      ss += __shfl_xor(ss, 4, 64);
      ss += __shfl_xor(ss, 8, 64);
      const float inv = rsqrtf(ss * (1.0f / 64.0f) + 1e-6f) * qmul;
      const float a0 = v0 * inv * scv[0];
      const float a1 = v1 * inv * scv[1];
      const float a2 = v2 * inv * scv[2];
      const float a3 = v3 * inv * scv[3];
      const int m = bm * 256 + M0 + mi * 16 + r0 + r;
      const int b = m >> 10, nn = m & 1023;
      const float2 tr = Tab[(nn >> 5) * 16 + lm];  // row-part angles
      const float2 tc = Tab[(nn & 31) * 16 + lm];  // col-part angles
      __half* row = base + ((long)((b * 16 + h) * 1024 + nn)) * 64 + lm;
      row[0]  = __float2half(a0 * tr.x - a2 * tr.y);
      row[16] = __float2half(a1 * tc.x - a3 * tc.y);
      row[32] = __float2half(a0 * tr.y + a2 * tr.x);
      row[48] = __float2half(a1 * tc.y + a3 * tc.x);
    }
  }
}

// ---------------------------------------------------------------------------
// out-projection: bf16 MFMA GEMM, single-barrier dbuf + XCD-stripe swizzle.
// ---------------------------------------------------------------------------
template<int MODE, int GX>
__global__ __launch_bounds__(256)
void gemm_bf16(const unsigned short* __restrict__ A,
               const unsigned short* __restrict__ Bt,
               const float* __restrict__ bias, float* __restrict__ Cf,
               __half* __restrict__ Ch, const float* __restrict__ qsc,
               const float* __restrict__ ksc) {
  __shared__ __align__(16) unsigned short As[2][4096];
  __shared__ __align__(16) unsigned short Bs[2][4096];
  const int t = threadIdx.x;
  const int flat = blockIdx.x + blockIdx.y * GX;
  const int xcd = flat & 7, j = flat >> 3;
  const int bm = xcd * 8 + (j & 7), bn = j >> 3;
  const int w = t >> 6, lane = t & 63;
  const int wm = (w & 1) << 6, wn = (w >> 1) << 6;
  const int lm = lane & 15, lk = (lane >> 4) << 3;

  const unsigned short* aptr =
      A + (long)(bm * 128 + (t >> 2)) * 1024 + ((t & 3) << 3);
  const unsigned short* bptr =
      Bt + (long)(bn * 128 + (t >> 2)) * 1024 + ((t & 3) << 3);

  f32x4 acc[4][4] = {};

  gload16(aptr, &As[0][t * 8]);
  gload16(aptr + 64 * 1024, &As[0][2048 + t * 8]);
  gload16(bptr, &Bs[0][t * 8]);
  gload16(bptr + 64 * 1024, &Bs[0][2048 + t * 8]);

  for (int it = 0; it < 32; ++it) {
    const int cur = it & 1;
    __syncthreads();
    if (it < 31) {
      const int nx = cur ^ 1;
      const int kk = (it + 1) * 32;
      gload16(aptr + kk, &As[nx][t * 8]);
      gload16(aptr + 64 * 1024 + kk, &As[nx][2048 + t * 8]);
      gload16(bptr + kk, &Bs[nx][t * 8]);
      gload16(bptr + 64 * 1024 + kk, &Bs[nx][2048 + t * 8]);
    }
    bf16x8 af[4], bfr[4];
#pragma unroll
    for (int mi = 0; mi < 4; ++mi)
      af[mi] = *(const bf16x8*)&As[cur][(wm + mi * 16 + lm) * 32 + lk];
#pragma unroll
    for (int ni = 0; ni < 4; ++ni)
      bfr[ni] = *(const bf16x8*)&Bs[cur][(wn + ni * 16 + lm) * 32 + lk];
#pragma unroll
    for (int mi = 0; mi < 4; ++mi)
#pragma unroll
      for (int ni = 0; ni < 4; ++ni)
        acc[mi][ni] = __builtin_amdgcn_mfma_f32_16x16x32_bf16(
            af[mi], bfr[ni], acc[mi][ni], 0, 0, 0);
  }

  const int r0 = (lane >> 4) << 2;
  const int nb = bn * 128 + wn;

#pragma unroll
  for (int mi = 0; mi < 4; ++mi)
#pragma unroll
    for (int ni = 0; ni < 4; ++ni) {
      const int n = nb + ni * 16 + lm;
      const float bvv = bias[n];
#pragma unroll
      for (int r = 0; r < 4; ++r)
        Cf[(long)(bm * 128 + wm + mi * 16 + r0 + r) * 1024 + n] =
            acc[mi][ni][r] + bvv;
    }
}

// ---------------------------------------------------------------------------
// MFMA flash attention (f16), fixed-offset softmax (exp2; log2e folded into
// q), single-barrier dbuf, 128 Q-rows per block. K/V fragments hoisted out
// of the group loop (read once per K-chunk, shared by both 16-row groups).
// ---------------------------------------------------------------------------
__global__ __launch_bounds__(256, 3)
void attn_mfma(const __half* __restrict__ qh, const __half* __restrict__ kh,
               const __half* __restrict__ vh, unsigned short* __restrict__ ob) {
  __shared__ __align__(16) __half Ks[2][4096];  // [krow][d] 64x64, swizzled
  __shared__ __align__(16) __half Vs[2][4096];  // [d][krow] 64x64, swizzled
  __shared__ __align__(16) __half Pl[8][1152];  // [wave*2+g][16 x 72]
  const int t = threadIdx.x;
  const int w = t >> 6, lane = t & 63;
  const int flat = blockIdx.x + blockIdx.y * 8;  // grid (8, 128)
  const int xcd = flat & 7, j = flat >> 3;       // j in [0,128)
  const int bh = xcd * 16 + (j >> 3);            // 16 heads per XCD
  const int qt = j & 7;                          // 128-row Q tile
  const int lm = lane & 15, q4 = lane >> 4;

  f16x8 qf[2][2];
#pragma unroll
  for (int g = 0; g < 2; ++g) {
    const __half* qrow =
        qh + ((long)(bh * 1024 + qt * 128 + g * 64 + w * 16 + lm)) * 64 +
        q4 * 8;
    qf[g][0] = *(const f16x8*)qrow;
    qf[g][1] = *(const f16x8*)(qrow + 32);
  }

  f32x4 o[2][4] = {};
  float l_r[2][4] = {};

  const int prow = t >> 3, pc = t & 7;
  const int scz = pc ^ (prow & 7);  // swizzled source chunk
  const __half* ksrc0 = kh + (long)(bh * 1024 + prow) * 64 + scz * 8;
  const __half* vsrc0 = vh + (long)(bh * 64 + prow) * 1024 + scz * 8;

  gload16(ksrc0, &Ks[0][t * 8]);
  gload16(ksrc0 + 32 * 64, &Ks[0][2048 + t * 8]);
  gload16(vsrc0, &Vs[0][t * 8]);
  gload16(vsrc0 + 32 * 1024, &Vs[0][2048 + t * 8]);

  for (int kc = 0; kc < 16; ++kc) {
    const int cur = kc & 1;
    __syncthreads();

    if (kc < 15) {
      const int nx = cur ^ 1;
      const __half* ksrc = ksrc0 + (kc + 1) * 4096;
      const __half* vsrc = vsrc0 + (kc + 1) * 64;
      gload16(ksrc, &Ks[nx][t * 8]);
      gload16(ksrc + 32 * 64, &Ks[nx][2048 + t * 8]);
      gload16(vsrc, &Vs[nx][t * 8]);
      gload16(vsrc + 32 * 1024, &Vs[nx][2048 + t * 8]);
    }

    // K fragments once per chunk, shared by both groups
    f16x8 kf[4][2];
#pragma unroll
    for (int nt = 0; nt < 4; ++nt) {
      const int kr = nt * 16 + lm;
#pragma unroll
      for (int ks = 0; ks < 2; ++ks)
        kf[nt][ks] = *(const f16x8*)&Ks[cur][kr * 64 +
                                      (((ks << 2) + q4) ^ (kr & 7)) * 8];
    }

    // S = Q K^T per group; softmax into per-group P strip
#pragma unroll
    for (int g = 0; g < 2; ++g) {
      f32x4 s[4];
      __builtin_amdgcn_s_setprio(1);
#pragma unroll
      for (int nt = 0; nt < 4; ++nt) {
        s[nt] = (f32x4){0.f, 0.f, 0.f, 0.f};
#pragma unroll
        for (int ks = 0; ks < 2; ++ks)
          s[nt] = __builtin_amdgcn_mfma_f32_16x16x32_f16(qf[g][ks], kf[nt][ks],
                                                         s[nt], 0, 0, 0);
      }
      __builtin_amdgcn_s_setprio(0);
      __half* Pw = &Pl[w * 2 + g][0];
#pragma unroll
      for (int nt = 0; nt < 4; ++nt) {
#pragma unroll
        for (int r = 0; r < 4; ++r) {
          const float p = exp2f(s[nt][r] - 12.98425536800067f);  // 9*log2(e)
          l_r[g][r] += p;
          Pw[(q4 * 4 + r) * 72 + nt * 16 + lm] = (__half)p;
        }
      }
    }

    // O += P V: V fragment read once, feeds both groups
    __builtin_amdgcn_s_setprio(1);
#pragma unroll
    for (int ks2 = 0; ks2 < 2; ++ks2) {
      const f16x8 pf0 = *(const f16x8*)&Pl[w * 2 + 0][lm * 72 + ks2 * 32 +
                                                      q4 * 8];
      const f16x8 pf1 = *(const f16x8*)&Pl[w * 2 + 1][lm * 72 + ks2 * 32 +
                                                      q4 * 8];
#pragma unroll
      for (int nt = 0; nt < 4; ++nt) {
        const int dr = nt * 16 + lm;
        const f16x8 vf = *(const f16x8*)&Vs[cur][dr * 64 +
                                          (((ks2 << 2) + q4) ^ (dr & 7)) * 8];
        o[0][nt] = __builtin_amdgcn_mfma_f32_16x16x32_f16(pf0, vf, o[0][nt],
                                                          0, 0, 0);
        o[1][nt] = __builtin_amdgcn_mfma_f32_16x16x32_f16(pf1, vf, o[1][nt],
                                                          0, 0, 0);
      }
    }
    __builtin_amdgcn_s_setprio(0);
  }

  const int b = bh >> 4, h = bh & 15;
#pragma unroll
  for (int g = 0; g < 2; ++g) {
#pragma unroll
    for (int r = 0; r < 4; ++r) {
      float l = l_r[g][r];
      l += __shfl_xor(l, 1, 64);
      l += __shfl_xor(l, 2, 64);
      l += __shfl_xor(l, 4, 64);
      l += __shfl_xor(l, 8, 64);
      const float linv = 1.0f / l;
      const long rowg =
          (long)(b * 1024 + qt * 128 + g * 64 + w * 16 + q4 * 4 + r) * 1024 +
          h * 64;
#pragma unroll
      for (int nt = 0; nt < 4; ++nt)
        ob[rowg + nt * 16 + lm] = f2bf(o[g][nt][r] * linv);
    }
  }
}

extern "C" void kernel_launch(void* const* d_in, const int* in_sizes, int n_in,
                              void* d_out, int out_size, void* d_ws,
                              size_t ws_size, hipStream_t stream) {
  const float* x    = (const float*)d_in[0];
  const float* Wqkv = (const float*)d_in[1];
  const float* bqkv = (const float*)d_in[2];
  const float* Wout = (const float*)d_in[3];
  const float* bout = (const float*)d_in[4];
  const float* qs   = (const float*)d_in[5];
  const float* ks   = (const float*)d_in[6];
  float* out = (float*)d_out;
  float* W = (float*)d_ws;  // 72 MB

  __half* qkvh = (__half*)W;            // q:0  k:+QSZ  vT:+2*QSZ (halfs)
  __half* qpre = qkvh;
  __half* kpre = qkvh + QSZ;
  __half* vT   = qkvh + 2 * QSZ;
  unsigned short* xb  = (unsigned short*)(W + 12582912);
  unsigned short* ob  = xb;
  unsigned short* wqT = (unsigned short*)(W + 16777216);
  unsigned short* woT = wqT + 3 * 1024 * 1024;

  cvt_bf16<<<4096, 256, 0, stream>>>(x, xb);
  cvt_t<<<dim3(96, 32), 256, 0, stream>>>(Wqkv, wqT, 3072);
  cvt_t<<<dim3(32, 32), 256, 0, stream>>>(Wout, woT, 1024);
  // 1) QKV projection + fused RMSNorm/RoPE (4-phase counted-vmcnt pipeline)
  gemm_qkv<<<384, 512, 0, stream>>>(xb, wqT, bqkv, qkvh, qs, ks);
  // 2) MFMA flash attention (128-row blocks) -> ob bf16 row-major
  attn_mfma<<<dim3(8, 128), 256, 0, stream>>>(qpre, kpre, vT, ob);
  // 3) output projection
  gemm_bf16<1, 8><<<dim3(8, 64), 256, 0, stream>>>(ob, woT, bout, out, nullptr,
                                                   nullptr, nullptr);
}

// Round 4
// 271.221 us; speedup vs baseline: 1.0173x; 1.0173x over previous
//
#include <hip/hip_runtime.h>
#include <hip/hip_bf16.h>
#include <hip/hip_fp16.h>
#include <math.h>

// B=8, H=16, N=1024, D=1024, hd=64
// ws layout (float units):
//   qpre f16 (B,H,N,64)   [0, 4M)        8M halfs   (normed+roped by gemm)
//   kpre f16 (B,H,N,64)   [4M, 8M)
//   vT   f16 (B,H,64,N)   [8M, 12M)      transposed per head
//   xb   bf16 [12M,16M)   (reused as ob after QKV gemm)
//   wqT  bf16 [16M,17.5M) ; woT bf16 [17.5M,18M)
// total 72 MB
#define QSZ 8388608  // halfs per q/k/v region

typedef short bf16x8 __attribute__((ext_vector_type(8)));
typedef _Float16 f16x8 __attribute__((ext_vector_type(8)));
typedef float f32x4 __attribute__((ext_vector_type(4)));

__device__ __forceinline__ unsigned short f2bf(float f) {
  __hip_bfloat16 h = __float2bfloat16(f);
  return *reinterpret_cast<unsigned short*>(&h);
}

__device__ __forceinline__ void gload16(const void* g, void* l) {
  __builtin_amdgcn_global_load_lds(
      (const __attribute__((address_space(1))) void*)g,
      (__attribute__((address_space(3))) void*)l, 16, 0, 0);
}

// ---------------------------------------------------------------------------
__global__ __launch_bounds__(256)
void cvt_bf16(const float* __restrict__ src, unsigned short* __restrict__ dst) {
  const int i = (blockIdx.x * 256 + threadIdx.x) * 8;
  const float4 a = *(const float4*)&src[i];
  const float4 b = *(const float4*)&src[i + 4];
  ushort4 lo, hi;
  lo.x = f2bf(a.x); lo.y = f2bf(a.y); lo.z = f2bf(a.z); lo.w = f2bf(a.w);
  hi.x = f2bf(b.x); hi.y = f2bf(b.y); hi.z = f2bf(b.z); hi.w = f2bf(b.w);
  *(ushort4*)&dst[i] = lo;
  *(ushort4*)&dst[i + 4] = hi;
}

// transpose+convert: src [1024,N] fp32 -> dst [N,1024] bf16
__global__ __launch_bounds__(256)
void cvt_t(const float* __restrict__ src, unsigned short* __restrict__ dst,
           const int N) {
  __shared__ unsigned short tile[32][33];
  const int k0 = blockIdx.y * 32, n0 = blockIdx.x * 32;
  const int t = threadIdx.x;
  const int r = t >> 3, c4 = (t & 7) * 4;
  const float4 v = *(const float4*)&src[(k0 + r) * N + n0 + c4];
  tile[r][c4 + 0] = f2bf(v.x);
  tile[r][c4 + 1] = f2bf(v.y);
  tile[r][c4 + 2] = f2bf(v.z);
  tile[r][c4 + 3] = f2bf(v.w);
  __syncthreads();
  ushort4 o;
  o.x = tile[c4 + 0][r];
  o.y = tile[c4 + 1][r];
  o.z = tile[c4 + 2][r];
  o.w = tile[c4 + 3][r];
  *(ushort4*)&dst[(long)(n0 + r) * 1024 + k0 + c4] = o;
}

// ---------------------------------------------------------------------------
// QKV projection: 256x256-tile bf16 GEMM, 4-phase counted-vmcnt pipeline.
// LDS = 4-slot ring of kk-half tiles (256 rows x 32 cols, A+B).
// Swizzle for 64-B rows: bank = (16r + 4c) mod 32; 16r mod 32 = 16(r&1), so
// parity splits the bank halves and the XOR must cycle WITHIN parity:
//   physical chunk = logical ^ ((r>>1)&3)
// -> 16 consecutive rows alias only 2-way per 16B slot (free, m136).
// Applied as inverse-swizzled global source + swizzled ds_read (LDS linear).
// Per K-tile: 4 phases {ds_read(8/4) + gload issue -> s_barrier ->
// lgkmcnt(0) -> setprio(1) 16xMFMA setprio(0) -> [vmcnt(8) ph1/ph3] ->
// s_barrier}. Loads never drain below 8 in the main loop.
// q is pre-scaled by hd^-0.5 * log2(e) so attention softmax is a bare exp2.
// ---------------------------------------------------------------------------
__global__ __launch_bounds__(512, 2)
void gemm_qkv(const unsigned short* __restrict__ A,
              const unsigned short* __restrict__ Bt,
              const float* __restrict__ bias,
              __half* __restrict__ Ch,
              const float* __restrict__ qsc,
              const float* __restrict__ ksc) {
  __shared__ __align__(16) unsigned short HA[4][8192];  // 4 half-slots A
  __shared__ __align__(16) unsigned short HB[4][8192];  // 4 half-slots B
  __shared__ float2 Tab[512];  // [pos 0..31][idx 0..15] cos/sin

  const int t = threadIdx.x;
  // bijective XCD swizzle (384 % 8 == 0): XCD x owns bm in [4x, 4x+4)
  const int swz = (blockIdx.x & 7) * 48 + (blockIdx.x >> 3);
  const int bm = swz / 12, bn = swz % 12;
  const int w = t >> 6, lane = t & 63;
  const int M0 = (w >> 2) * 128, N0 = (w & 3) * 64;
  const int lm = lane & 15, q4 = lane >> 4;

  {  // RoPE table: one entry per thread (ds_write retires at first lgkmcnt)
    const int pos = t >> 4, idx = t & 15;
    const float invf = expf(-(float)idx * 0.57564627324851149f);
    const float ang = (float)pos * invf;
    Tab[t] = make_float2(cosf(ang), sinf(ang));
  }

  // staging: thread t covers rows (t>>2), (t>>2)+128; physical chunk t&3.
  // inverse swizzle: logical chunk = (t&3) ^ ((row>>1)&3) = (t&3)^((t>>3)&3)
  // (same for row+128 since (128>>1)&3 == 0).
  const int c8 = (((t & 3) ^ ((t >> 3) & 3)) << 3);
  const unsigned short* aSrc = A + (long)(bm * 256 + (t >> 2)) * 1024 + c8;
  const unsigned short* bSrc = Bt + (long)(bn * 256 + (t >> 2)) * 1024 + c8;

  f32x4 acc[8][4] = {};

  auto stageA = [&](int G) {  // half-tile G of A: 2 gload_lds per thread
    const unsigned short* a = aSrc + ((G >> 1) << 6) + ((G & 1) << 5);
    unsigned short* la = &HA[G & 3][t * 8];
    gload16(a, la);
    gload16(a + 128 * 1024, la + 4096);
  };
  auto stageB = [&](int G) {
    const unsigned short* b = bSrc + ((G >> 1) << 6) + ((G & 1) << 5);
    unsigned short* lb = &HB[G & 3][t * 8];
    gload16(b, lb);
    gload16(b + 128 * 1024, lb + 4096);
  };

  auto rdA4 = [&](bf16x8* dst, int slot, int mi0) {
#pragma unroll
    for (int i = 0; i < 4; ++i) {
      const int r = M0 + (mi0 + i) * 16 + lm;
      dst[i] = *(const bf16x8*)
          &HA[slot][r * 32 + ((q4 ^ ((lm >> 1) & 3)) << 3)];
    }
  };
  auto rdB4 = [&](bf16x8* dst, int slot) {
#pragma unroll
    for (int i = 0; i < 4; ++i) {
      const int r = N0 + i * 16 + lm;
      dst[i] = *(const bf16x8*)
          &HB[slot][r * 32 + ((q4 ^ ((lm >> 1) & 3)) << 3)];
    }
  };
  auto mfmaQ = [&](const bf16x8* fa, const bf16x8* fb, int mb) {
    __builtin_amdgcn_s_setprio(1);
#pragma unroll
    for (int mi = 0; mi < 4; ++mi)
#pragma unroll
      for (int ni = 0; ni < 4; ++ni)
        acc[mb + mi][ni] = __builtin_amdgcn_mfma_f32_16x16x32_bf16(
            fa[mi], fb[ni], acc[mb + mi][ni], 0, 0, 0);
    __builtin_amdgcn_s_setprio(0);
  };
  auto bar = [] { __builtin_amdgcn_s_barrier(); };
  auto lgkm0 = [] {
    asm volatile("s_waitcnt lgkmcnt(0)" ::: "memory");
  };

  // prologue: halves G0,G1,G2 in flight (12 loads); wait G0 (12 -> 8)
  stageA(0); stageB(0);
  stageA(1); stageB(1);
  stageA(2); stageB(2);
  asm volatile("s_waitcnt vmcnt(8)" ::: "memory");
  bar();

  bf16x8 fa[4], fb[4], fa2[4];
  for (int kt = 0; kt < 14; ++kt) {
    const int h0 = (2 * kt) & 3, h1 = (2 * kt + 1) & 3;
    // ph0: kk0, mi 0-3
    rdA4(fa, h0, 0); rdB4(fb, h0);
    stageA(2 * kt + 3);
    bar(); lgkm0(); mfmaQ(fa, fb, 0); bar();
    // ph1: kk0, mi 4-7
    rdA4(fa2, h0, 4);
    stageB(2 * kt + 3);
    bar(); lgkm0(); mfmaQ(fa2, fb, 4);
    asm volatile("s_waitcnt vmcnt(8)" ::: "memory");  // retire G=2kt+1
    bar();
    // ph2: kk1, mi 0-3
    rdA4(fa, h1, 0); rdB4(fb, h1);
    stageA(2 * kt + 4);
    bar(); lgkm0(); mfmaQ(fa, fb, 0); bar();
    // ph3: kk1, mi 4-7
    rdA4(fa2, h1, 4);
    stageB(2 * kt + 4);
    bar(); lgkm0(); mfmaQ(fa2, fb, 4);
    asm volatile("s_waitcnt vmcnt(8)" ::: "memory");  // retire G=2kt+2
    bar();
  }
  {  // kt = 14: stage G31 only; end-ph3 wait vmcnt(4) (retire G30)
    rdA4(fa, 0, 0); rdB4(fb, 0);
    stageA(31);
    bar(); lgkm0(); mfmaQ(fa, fb, 0); bar();
    rdA4(fa2, 0, 4);
    stageB(31);
    bar(); lgkm0(); mfmaQ(fa2, fb, 4);
    asm volatile("s_waitcnt vmcnt(8)" ::: "memory");  // retire G29
    bar();
    rdA4(fa, 1, 0); rdB4(fb, 1);
    bar(); lgkm0(); mfmaQ(fa, fb, 0); bar();
    rdA4(fa2, 1, 4);
    bar(); lgkm0(); mfmaQ(fa2, fb, 4);
    asm volatile("s_waitcnt vmcnt(4)" ::: "memory");  // retire G30
    bar();
  }
  {  // kt = 15: no staging; end-ph1 wait vmcnt(0) (retire G31)
    rdA4(fa, 2, 0); rdB4(fb, 2);
    bar(); lgkm0(); mfmaQ(fa, fb, 0); bar();
    rdA4(fa2, 2, 4);
    bar(); lgkm0(); mfmaQ(fa2, fb, 4);
    asm volatile("s_waitcnt vmcnt(0)" ::: "memory");  // retire G31
    bar();
    rdA4(fa, 3, 0); rdB4(fb, 3);
    bar(); lgkm0(); mfmaQ(fa, fb, 0); bar();
    rdA4(fa2, 3, 4);
    bar(); lgkm0(); mfmaQ(fa2, fb, 4);
  }

  // ---- fused epilogue (wave col-span = one head) ----
  const int r0 = q4 << 2;
  const int nb = bn * 256 + N0;
  const int tq = nb >> 10, h = (nb >> 6) & 15;

  if (tq == 2) {  // v: f16 transpose-scatter (B,H,64,N)
#pragma unroll
    for (int mi = 0; mi < 8; ++mi)
#pragma unroll
      for (int ni = 0; ni < 4; ++ni) {
        const int col = nb + ni * 16 + lm;
        const int dd = col & 63;
        const float bv = bias[col];
#pragma unroll
        for (int r = 0; r < 4; ++r) {
          const int m = bm * 256 + M0 + mi * 16 + r0 + r;
          const int b = m >> 10, nn = m & 1023;
          Ch[2L * QSZ + ((long)((b * 16 + h) * 64 + dd)) * 1024 + nn] =
              __float2half(acc[mi][ni][r] + bv);
        }
      }
    return;
  }

  // q or k: RMSNorm + RoPE on f32 accs, then f16 store (B,H,N,64)
  const float* scp = (tq == 0) ? qsc : ksc;
  // q: fold hd^-0.5 AND log2(e) (softmax uses exp2) into the stored q
  const float qmul = (tq == 0) ? 0.18033688011112042f : 1.0f;
  float scv[4], bv[4];
#pragma unroll
  for (int ni = 0; ni < 4; ++ni) {
    scv[ni] = scp[ni * 16 + lm];
    bv[ni] = bias[nb + ni * 16 + lm];
  }
  __half* base = Ch + (long)tq * QSZ;
#pragma unroll
  for (int mi = 0; mi < 8; ++mi) {
#pragma unroll
    for (int r = 0; r < 4; ++r) {
      const float v0 = acc[mi][0][r] + bv[0];
      const float v1 = acc[mi][1][r] + bv[1];
      const float v2 = acc[mi][2][r] + bv[2];
      const float v3 = acc[mi][3][r] + bv[3];
      float ss = v0 * v0 + v1 * v1 + v2 * v2 + v3 * v3;
      ss += __shfl_xor(ss, 1, 64);
      ss += __shfl_xor(ss, 2, 64);
      ss += __shfl_xor(ss, 4, 64);
      ss += __shfl_xor(ss, 8, 64);
      const float inv = rsqrtf(ss * (1.0f / 64.0f) + 1e-6f) * qmul;
      const float a0 = v0 * inv * scv[0];
      const float a1 = v1 * inv * scv[1];
      const float a2 = v2 * inv * scv[2];
      const float a3 = v3 * inv * scv[3];
      const int m = bm * 256 + M0 + mi * 16 + r0 + r;
      const int b = m >> 10, nn = m & 1023;
      const float2 tr = Tab[(nn >> 5) * 16 + lm];  // row-part angles
      const float2 tc = Tab[(nn & 31) * 16 + lm];  // col-part angles
      __half* row = base + ((long)((b * 16 + h) * 1024 + nn)) * 64 + lm;
      row[0]  = __float2half(a0 * tr.x - a2 * tr.y);
      row[16] = __float2half(a1 * tc.x - a3 * tc.y);
      row[32] = __float2half(a0 * tr.y + a2 * tr.x);
      row[48] = __float2half(a1 * tc.y + a3 * tc.x);
    }
  }
}

// ---------------------------------------------------------------------------
// out-projection: bf16 MFMA GEMM, single-barrier dbuf + XCD-stripe swizzle.
// ---------------------------------------------------------------------------
template<int MODE, int GX>
__global__ __launch_bounds__(256)
void gemm_bf16(const unsigned short* __restrict__ A,
               const unsigned short* __restrict__ Bt,
               const float* __restrict__ bias, float* __restrict__ Cf,
               __half* __restrict__ Ch, const float* __restrict__ qsc,
               const float* __restrict__ ksc) {
  __shared__ __align__(16) unsigned short As[2][4096];
  __shared__ __align__(16) unsigned short Bs[2][4096];
  const int t = threadIdx.x;
  const int flat = blockIdx.x + blockIdx.y * GX;
  const int xcd = flat & 7, j = flat >> 3;
  const int bm = xcd * 8 + (j & 7), bn = j >> 3;
  const int w = t >> 6, lane = t & 63;
  const int wm = (w & 1) << 6, wn = (w >> 1) << 6;
  const int lm = lane & 15, lk = (lane >> 4) << 3;

  const unsigned short* aptr =
      A + (long)(bm * 128 + (t >> 2)) * 1024 + ((t & 3) << 3);
  const unsigned short* bptr =
      Bt + (long)(bn * 128 + (t >> 2)) * 1024 + ((t & 3) << 3);

  f32x4 acc[4][4] = {};

  gload16(aptr, &As[0][t * 8]);
  gload16(aptr + 64 * 1024, &As[0][2048 + t * 8]);
  gload16(bptr, &Bs[0][t * 8]);
  gload16(bptr + 64 * 1024, &Bs[0][2048 + t * 8]);

  for (int it = 0; it < 32; ++it) {
    const int cur = it & 1;
    __syncthreads();
    if (it < 31) {
      const int nx = cur ^ 1;
      const int kk = (it + 1) * 32;
      gload16(aptr + kk, &As[nx][t * 8]);
      gload16(aptr + 64 * 1024 + kk, &As[nx][2048 + t * 8]);
      gload16(bptr + kk, &Bs[nx][t * 8]);
      gload16(bptr + 64 * 1024 + kk, &Bs[nx][2048 + t * 8]);
    }
    bf16x8 af[4], bfr[4];
#pragma unroll
    for (int mi = 0; mi < 4; ++mi)
      af[mi] = *(const bf16x8*)&As[cur][(wm + mi * 16 + lm) * 32 + lk];
#pragma unroll
    for (int ni = 0; ni < 4; ++ni)
      bfr[ni] = *(const bf16x8*)&Bs[cur][(wn + ni * 16 + lm) * 32 + lk];
#pragma unroll
    for (int mi = 0; mi < 4; ++mi)
#pragma unroll
      for (int ni = 0; ni < 4; ++ni)
        acc[mi][ni] = __builtin_amdgcn_mfma_f32_16x16x32_bf16(
            af[mi], bfr[ni], acc[mi][ni], 0, 0, 0);
  }

  const int r0 = (lane >> 4) << 2;
  const int nb = bn * 128 + wn;

#pragma unroll
  for (int mi = 0; mi < 4; ++mi)
#pragma unroll
    for (int ni = 0; ni < 4; ++ni) {
      const int n = nb + ni * 16 + lm;
      const float bvv = bias[n];
#pragma unroll
      for (int r = 0; r < 4; ++r)
        Cf[(long)(bm * 128 + wm + mi * 16 + r0 + r) * 1024 + n] =
            acc[mi][ni][r] + bvv;
    }
}

// ---------------------------------------------------------------------------
// MFMA flash attention (f16), fixed-offset softmax (exp2; log2e folded into
// q), single-barrier dbuf, 128 Q-rows per block. K/V fragments hoisted out
// of the group loop (read once per K-chunk, shared by both 16-row groups).
// ---------------------------------------------------------------------------
__global__ __launch_bounds__(256, 3)
void attn_mfma(const __half* __restrict__ qh, const __half* __restrict__ kh,
               const __half* __restrict__ vh, unsigned short* __restrict__ ob) {
  __shared__ __align__(16) __half Ks[2][4096];  // [krow][d] 64x64, swizzled
  __shared__ __align__(16) __half Vs[2][4096];  // [d][krow] 64x64, swizzled
  __shared__ __align__(16) __half Pl[8][1152];  // [wave*2+g][16 x 72]
  const int t = threadIdx.x;
  const int w = t >> 6, lane = t & 63;
  const int flat = blockIdx.x + blockIdx.y * 8;  // grid (8, 128)
  const int xcd = flat & 7, j = flat >> 3;       // j in [0,128)
  const int bh = xcd * 16 + (j >> 3);            // 16 heads per XCD
  const int qt = j & 7;                          // 128-row Q tile
  const int lm = lane & 15, q4 = lane >> 4;

  f16x8 qf[2][2];
#pragma unroll
  for (int g = 0; g < 2; ++g) {
    const __half* qrow =
        qh + ((long)(bh * 1024 + qt * 128 + g * 64 + w * 16 + lm)) * 64 +
        q4 * 8;
    qf[g][0] = *(const f16x8*)qrow;
    qf[g][1] = *(const f16x8*)(qrow + 32);
  }

  f32x4 o[2][4] = {};
  float l_r[2][4] = {};

  const int prow = t >> 3, pc = t & 7;
  const int scz = pc ^ (prow & 7);  // swizzled source chunk
  const __half* ksrc0 = kh + (long)(bh * 1024 + prow) * 64 + scz * 8;
  const __half* vsrc0 = vh + (long)(bh * 64 + prow) * 1024 + scz * 8;

  gload16(ksrc0, &Ks[0][t * 8]);
  gload16(ksrc0 + 32 * 64, &Ks[0][2048 + t * 8]);
  gload16(vsrc0, &Vs[0][t * 8]);
  gload16(vsrc0 + 32 * 1024, &Vs[0][2048 + t * 8]);

  for (int kc = 0; kc < 16; ++kc) {
    const int cur = kc & 1;
    __syncthreads();

    if (kc < 15) {
      const int nx = cur ^ 1;
      const __half* ksrc = ksrc0 + (kc + 1) * 4096;
      const __half* vsrc = vsrc0 + (kc + 1) * 64;
      gload16(ksrc, &Ks[nx][t * 8]);
      gload16(ksrc + 32 * 64, &Ks[nx][2048 + t * 8]);
      gload16(vsrc, &Vs[nx][t * 8]);
      gload16(vsrc + 32 * 1024, &Vs[nx][2048 + t * 8]);
    }

    // K fragments once per chunk, shared by both groups
    f16x8 kf[4][2];
#pragma unroll
    for (int nt = 0; nt < 4; ++nt) {
      const int kr = nt * 16 + lm;
#pragma unroll
      for (int ks = 0; ks < 2; ++ks)
        kf[nt][ks] = *(const f16x8*)&Ks[cur][kr * 64 +
                                      (((ks << 2) + q4) ^ (kr & 7)) * 8];
    }

    // S = Q K^T per group; softmax into per-group P strip
#pragma unroll
    for (int g = 0; g < 2; ++g) {
      f32x4 s[4];
      __builtin_amdgcn_s_setprio(1);
#pragma unroll
      for (int nt = 0; nt < 4; ++nt) {
        s[nt] = (f32x4){0.f, 0.f, 0.f, 0.f};
#pragma unroll
        for (int ks = 0; ks < 2; ++ks)
          s[nt] = __builtin_amdgcn_mfma_f32_16x16x32_f16(qf[g][ks], kf[nt][ks],
                                                         s[nt], 0, 0, 0);
      }
      __builtin_amdgcn_s_setprio(0);
      __half* Pw = &Pl[w * 2 + g][0];
#pragma unroll
      for (int nt = 0; nt < 4; ++nt) {
#pragma unroll
        for (int r = 0; r < 4; ++r) {
          const float p = exp2f(s[nt][r] - 12.98425536800067f);  // 9*log2(e)
          l_r[g][r] += p;
          Pw[(q4 * 4 + r) * 72 + nt * 16 + lm] = (__half)p;
        }
      }
    }

    // O += P V: V fragment read once, feeds both groups
    __builtin_amdgcn_s_setprio(1);
#pragma unroll
    for (int ks2 = 0; ks2 < 2; ++ks2) {
      const f16x8 pf0 = *(const f16x8*)&Pl[w * 2 + 0][lm * 72 + ks2 * 32 +
                                                      q4 * 8];
      const f16x8 pf1 = *(const f16x8*)&Pl[w * 2 + 1][lm * 72 + ks2 * 32 +
                                                      q4 * 8];
#pragma unroll
      for (int nt = 0; nt < 4; ++nt) {
        const int dr = nt * 16 + lm;
        const f16x8 vf = *(const f16x8*)&Vs[cur][dr * 64 +
                                          (((ks2 << 2) + q4) ^ (dr & 7)) * 8];
        o[0][nt] = __builtin_amdgcn_mfma_f32_16x16x32_f16(pf0, vf, o[0][nt],
                                                          0, 0, 0);
        o[1][nt] = __builtin_amdgcn_mfma_f32_16x16x32_f16(pf1, vf, o[1][nt],
                                                          0, 0, 0);
      }
    }
    __builtin_amdgcn_s_setprio(0);
  }

  const int b = bh >> 4, h = bh & 15;
#pragma unroll
  for (int g = 0; g < 2; ++g) {
#pragma unroll
    for (int r = 0; r < 4; ++r) {
      float l = l_r[g][r];
      l += __shfl_xor(l, 1, 64);
      l += __shfl_xor(l, 2, 64);
      l += __shfl_xor(l, 4, 64);
      l += __shfl_xor(l, 8, 64);
      const float linv = 1.0f / l;
      const long rowg =
          (long)(b * 1024 + qt * 128 + g * 64 + w * 16 + q4 * 4 + r) * 1024 +
          h * 64;
#pragma unroll
      for (int nt = 0; nt < 4; ++nt)
        ob[rowg + nt * 16 + lm] = f2bf(o[g][nt][r] * linv);
    }
  }
}

extern "C" void kernel_launch(void* const* d_in, const int* in_sizes, int n_in,
                              void* d_out, int out_size, void* d_ws,
                              size_t ws_size, hipStream_t stream) {
  const float* x    = (const float*)d_in[0];
  const float* Wqkv = (const float*)d_in[1];
  const float* bqkv = (const float*)d_in[2];
  const float* Wout = (const float*)d_in[3];
  const float* bout = (const float*)d_in[4];
  const float* qs   = (const float*)d_in[5];
  const float* ks   = (const float*)d_in[6];
  float* out = (float*)d_out;
  float* W = (float*)d_ws;  // 72 MB

  __half* qkvh = (__half*)W;            // q:0  k:+QSZ  vT:+2*QSZ (halfs)
  __half* qpre = qkvh;
  __half* kpre = qkvh + QSZ;
  __half* vT   = qkvh + 2 * QSZ;
  unsigned short* xb  = (unsigned short*)(W + 12582912);
  unsigned short* ob  = xb;
  unsigned short* wqT = (unsigned short*)(W + 16777216);
  unsigned short* woT = wqT + 3 * 1024 * 1024;

  cvt_bf16<<<4096, 256, 0, stream>>>(x, xb);
  cvt_t<<<dim3(96, 32), 256, 0, stream>>>(Wqkv, wqT, 3072);
  cvt_t<<<dim3(32, 32), 256, 0, stream>>>(Wout, woT, 1024);
  // 1) QKV projection + fused RMSNorm/RoPE (4-phase counted-vmcnt pipeline)
  gemm_qkv<<<384, 512, 0, stream>>>(xb, wqT, bqkv, qkvh, qs, ks);
  // 2) MFMA flash attention (128-row blocks) -> ob bf16 row-major
  attn_mfma<<<dim3(8, 128), 256, 0, stream>>>(qpre, kpre, vT, ob);
  // 3) output projection
  gemm_bf16<1, 8><<<dim3(8, 64), 256, 0, stream>>>(ob, woT, bout, out, nullptr,
                                                   nullptr, nullptr);
}

// Round 5
// 268.131 us; speedup vs baseline: 1.0290x; 1.0115x over previous
//
#include <hip/hip_runtime.h>
#include <hip/hip_bf16.h>
#include <hip/hip_fp16.h>
#include <math.h>

// B=8, H=16, N=1024, D=1024, hd=64
// ws layout (float units):
//   qpre f16 (B,H,N,64)   [0, 4M)        8M halfs   (normed+roped by gemm)
//   kpre f16 (B,H,N,64)   [4M, 8M)
//   vT   f16 (B,H,64,N)   [8M, 12M)      transposed per head
//   xb   bf16 [12M,16M)   (reused as ob after QKV gemm)
//   wqT  bf16 [16M,17.5M) ; woT bf16 [17.5M,18M)
// total 72 MB
#define QSZ 8388608  // halfs per q/k/v region

typedef short bf16x8 __attribute__((ext_vector_type(8)));
typedef _Float16 f16x8 __attribute__((ext_vector_type(8)));
typedef float f32x4 __attribute__((ext_vector_type(4)));

__device__ __forceinline__ unsigned short f2bf(float f) {
  __hip_bfloat16 h = __float2bfloat16(f);
  return *reinterpret_cast<unsigned short*>(&h);
}

__device__ __forceinline__ void gload16(const void* g, void* l) {
  __builtin_amdgcn_global_load_lds(
      (const __attribute__((address_space(1))) void*)g,
      (__attribute__((address_space(3))) void*)l, 16, 0, 0);
}

// ---------------------------------------------------------------------------
__global__ __launch_bounds__(256)
void cvt_bf16(const float* __restrict__ src, unsigned short* __restrict__ dst) {
  const int i = (blockIdx.x * 256 + threadIdx.x) * 8;
  const float4 a = *(const float4*)&src[i];
  const float4 b = *(const float4*)&src[i + 4];
  ushort4 lo, hi;
  lo.x = f2bf(a.x); lo.y = f2bf(a.y); lo.z = f2bf(a.z); lo.w = f2bf(a.w);
  hi.x = f2bf(b.x); hi.y = f2bf(b.y); hi.z = f2bf(b.z); hi.w = f2bf(b.w);
  *(ushort4*)&dst[i] = lo;
  *(ushort4*)&dst[i + 4] = hi;
}

// transpose+convert: src [1024,N] fp32 -> dst [N,1024] bf16
__global__ __launch_bounds__(256)
void cvt_t(const float* __restrict__ src, unsigned short* __restrict__ dst,
           const int N) {
  __shared__ unsigned short tile[32][33];
  const int k0 = blockIdx.y * 32, n0 = blockIdx.x * 32;
  const int t = threadIdx.x;
  const int r = t >> 3, c4 = (t & 7) * 4;
  const float4 v = *(const float4*)&src[(k0 + r) * N + n0 + c4];
  tile[r][c4 + 0] = f2bf(v.x);
  tile[r][c4 + 1] = f2bf(v.y);
  tile[r][c4 + 2] = f2bf(v.z);
  tile[r][c4 + 3] = f2bf(v.w);
  __syncthreads();
  ushort4 o;
  o.x = tile[c4 + 0][r];
  o.y = tile[c4 + 1][r];
  o.z = tile[c4 + 2][r];
  o.w = tile[c4 + 3][r];
  *(ushort4*)&dst[(long)(n0 + r) * 1024 + k0 + c4] = o;
}

// ---------------------------------------------------------------------------
// 256x256-tile counted-vmcnt deep-pipeline bf16 GEMM (coarse 2-barrier
// schedule -- the R1-proven structure; 4-phase variants measured slower):
//   - 512 threads = 8 waves (2M x 4N), per-wave 128x64 output, BK=64
//   - LDS: 2 x (256x64) A + 2 x (256x64) B; 128-B rows with 3-bit XOR
//     swizzle (chunk ^= row&7) applied as inverse-swizzled global source +
//     swizzled ds_read (rows start at bank 0; 8 chunks span all 32 banks;
//     16 lanes/frag alias only 2-way = free). Conflicts measured ~184K.
//   - raw s_barrier + manual s_waitcnt; vmcnt(8) steady state (tile t+2's
//     8 loads stay in flight across both barriers; never drained to 0)
// MODE 0 (QKV, grid 384 = 32bm x 12bn): fused RMSNorm + 2D-RoPE epilogue;
//   q/k f16 (B,H,N,64), v f16 transposed (B,H,64,N). Wave col-span = 1 head.
//   q pre-scaled by hd^-0.5 * log2(e) so attention softmax is a bare exp2.
// MODE 1 (out-proj, grid 128 = 32bm x 4bn): fp32 row-major + bias.
//   128 blocks -> single dispatch round, no tail.
// ---------------------------------------------------------------------------
template<int MODE>
__global__ __launch_bounds__(512, 2)
void gemm256(const unsigned short* __restrict__ A,
             const unsigned short* __restrict__ Bt,
             const float* __restrict__ bias,
             float* __restrict__ Cf,
             __half* __restrict__ Ch,
             const float* __restrict__ qsc,
             const float* __restrict__ ksc) {
  __shared__ __align__(16) unsigned short As[2][16384];
  __shared__ __align__(16) unsigned short Bs[2][16384];
  __shared__ float2 Tab[512];  // [pos 0..31][idx 0..15] cos/sin (MODE 0)

  constexpr int GXN = (MODE == 0) ? 12 : 4;   // bn tiles
  constexpr int CPX = (MODE == 0) ? 48 : 16;  // blocks per XCD (nwg/8)

  const int t = threadIdx.x;
  // bijective XCD swizzle (nwg % 8 == 0)
  const int swz = (blockIdx.x & 7) * CPX + (blockIdx.x >> 3);
  const int bm = swz / GXN, bn = swz % GXN;
  const int w = t >> 6, lane = t & 63;
  const int M0 = (w >> 2) * 128, N0 = (w & 3) * 64;
  const int lm = lane & 15, q4 = lane >> 4;

  if (MODE == 0) {  // RoPE table (visible after prologue barrier)
    const int pos = t >> 4, idx = t & 15;
    const float invf = expf(-(float)idx * 0.57564627324851149f);
    const float ang = (float)pos * invf;
    Tab[t] = make_float2(cosf(ang), sinf(ang));
  }

  // staging: thread t writes LDS row (j*64 + t>>3), 16B chunk (t&7).
  // inverse swizzle on the global source so swizzled reads see logical data.
  const int c8 = ((t & 7) ^ ((t >> 3) & 7)) << 3;
  const unsigned short* aSrc = A + (long)(bm * 256 + (t >> 3)) * 1024 + c8;
  const unsigned short* bSrc = Bt + (long)(bn * 256 + (t >> 3)) * 1024 + c8;
  unsigned short* lA[2] = {&As[0][t * 8], &As[1][t * 8]};
  unsigned short* lB[2] = {&Bs[0][t * 8], &Bs[1][t * 8]};

  f32x4 acc[8][4] = {};

  auto stage = [&](int buf, int kt) {  // 8 gload_lds per thread = one K-tile
    const unsigned short* a = aSrc + kt * 64;
    const unsigned short* b = bSrc + kt * 64;
    unsigned short* la = lA[buf];
    unsigned short* lb = lB[buf];
#pragma unroll
    for (int j = 0; j < 4; ++j) {
      gload16(a + j * 65536, la + j * 4096);
      gload16(b + j * 65536, lb + j * 4096);
    }
  };

  auto compute = [&](const unsigned short* Ac, const unsigned short* Bc) {
#pragma unroll
    for (int kk = 0; kk < 2; ++kk) {
      bf16x8 af[8], bg[4];
#pragma unroll
      for (int mi = 0; mi < 8; ++mi) {
        const int row = M0 + mi * 16 + lm;
        af[mi] = *(const bf16x8*)
            &Ac[row * 64 + ((((kk << 2) + q4) ^ (row & 7)) << 3)];
      }
#pragma unroll
      for (int ni = 0; ni < 4; ++ni) {
        const int row = N0 + ni * 16 + lm;
        bg[ni] = *(const bf16x8*)
            &Bc[row * 64 + ((((kk << 2) + q4) ^ (row & 7)) << 3)];
      }
#pragma unroll
      for (int mi = 0; mi < 8; ++mi)
#pragma unroll
        for (int ni = 0; ni < 4; ++ni)
          acc[mi][ni] = __builtin_amdgcn_mfma_f32_16x16x32_bf16(
              af[mi], bg[ni], acc[mi][ni], 0, 0, 0);
    }
  };

  // prologue: tiles 0,1 in flight; wait tile 0 (vmcnt: 16 out -> 8 = tile1)
  stage(0, 0);
  stage(1, 1);
  asm volatile("s_waitcnt vmcnt(8)" ::: "memory");
  __builtin_amdgcn_s_barrier();

  // steady state: compute tile kt from buf[s]; after all waves finished
  // reading buf[s] (lgkmcnt(0) + barrier), issue tile kt+2 into buf[s];
  // vmcnt(8) retires exactly tile kt+1's loads; 8 loads cross the barrier.
  for (int kt = 0; kt < 14; ++kt) {
    const int s = kt & 1;
    compute(s ? &As[1][0] : &As[0][0], s ? &Bs[1][0] : &Bs[0][0]);
    asm volatile("s_waitcnt lgkmcnt(0)" ::: "memory");
    __builtin_amdgcn_s_barrier();
    stage(s, kt + 2);
    asm volatile("s_waitcnt vmcnt(8)" ::: "memory");
    __builtin_amdgcn_s_barrier();
  }
  compute(&As[0][0], &Bs[0][0]);
  asm volatile("s_waitcnt lgkmcnt(0)" ::: "memory");
  __builtin_amdgcn_s_barrier();
  asm volatile("s_waitcnt vmcnt(0)" ::: "memory");
  __builtin_amdgcn_s_barrier();
  compute(&As[1][0], &Bs[1][0]);

  // ---- epilogues ----
  const int r0 = q4 << 2;
  const int nb = bn * 256 + N0;

  if (MODE == 1) {  // out-proj: fp32 row-major + bias
#pragma unroll
    for (int mi = 0; mi < 8; ++mi)
#pragma unroll
      for (int ni = 0; ni < 4; ++ni) {
        const int n = nb + ni * 16 + lm;
        const float bvv = bias[n];
#pragma unroll
        for (int r = 0; r < 4; ++r)
          Cf[(long)(bm * 256 + M0 + mi * 16 + r0 + r) * 1024 + n] =
              acc[mi][ni][r] + bvv;
      }
    return;
  }

  // MODE 0 fused epilogue (wave col-span = one head)
  const int tq = nb >> 10, h = (nb >> 6) & 15;

  if (tq == 2) {  // v: f16 transpose-scatter (B,H,64,N)
#pragma unroll
    for (int mi = 0; mi < 8; ++mi)
#pragma unroll
      for (int ni = 0; ni < 4; ++ni) {
        const int col = nb + ni * 16 + lm;
        const int dd = col & 63;
        const float bv = bias[col];
#pragma unroll
        for (int r = 0; r < 4; ++r) {
          const int m = bm * 256 + M0 + mi * 16 + r0 + r;
          const int b = m >> 10, nn = m & 1023;
          Ch[2L * QSZ + ((long)((b * 16 + h) * 64 + dd)) * 1024 + nn] =
              __float2half(acc[mi][ni][r] + bv);
        }
      }
    return;
  }

  // q or k: RMSNorm + RoPE on f32 accs, then f16 store (B,H,N,64)
  const float* scp = (tq == 0) ? qsc : ksc;
  // q: fold hd^-0.5 AND log2(e) (softmax uses exp2) into the stored q
  const float qmul = (tq == 0) ? 0.18033688011112042f : 1.0f;
  float scv[4], bv[4];
#pragma unroll
  for (int ni = 0; ni < 4; ++ni) {
    scv[ni] = scp[ni * 16 + lm];
    bv[ni] = bias[nb + ni * 16 + lm];
  }
  __half* base = Ch + (long)tq * QSZ;
#pragma unroll
  for (int mi = 0; mi < 8; ++mi) {
#pragma unroll
    for (int r = 0; r < 4; ++r) {
      const float v0 = acc[mi][0][r] + bv[0];
      const float v1 = acc[mi][1][r] + bv[1];
      const float v2 = acc[mi][2][r] + bv[2];
      const float v3 = acc[mi][3][r] + bv[3];
      float ss = v0 * v0 + v1 * v1 + v2 * v2 + v3 * v3;
      ss += __shfl_xor(ss, 1, 64);
      ss += __shfl_xor(ss, 2, 64);
      ss += __shfl_xor(ss, 4, 64);
      ss += __shfl_xor(ss, 8, 64);
      const float inv = rsqrtf(ss * (1.0f / 64.0f) + 1e-6f) * qmul;
      const float a0 = v0 * inv * scv[0];
      const float a1 = v1 * inv * scv[1];
      const float a2 = v2 * inv * scv[2];
      const float a3 = v3 * inv * scv[3];
      const int m = bm * 256 + M0 + mi * 16 + r0 + r;
      const int b = m >> 10, nn = m & 1023;
      const float2 tr = Tab[(nn >> 5) * 16 + lm];  // row-part angles
      const float2 tc = Tab[(nn & 31) * 16 + lm];  // col-part angles
      __half* row = base + ((long)((b * 16 + h) * 1024 + nn)) * 64 + lm;
      row[0]  = __float2half(a0 * tr.x - a2 * tr.y);
      row[16] = __float2half(a1 * tc.x - a3 * tc.y);
      row[32] = __float2half(a0 * tr.y + a2 * tr.x);
      row[48] = __float2half(a1 * tc.y + a3 * tc.x);
    }
  }
}

// ---------------------------------------------------------------------------
// MFMA flash attention (f16), fixed-offset softmax (exp2; log2e folded into
// q), single-barrier dbuf, 128 Q-rows per block. K/V fragments hoisted out
// of the group loop (read once per K-chunk, shared by both 16-row groups).
// ---------------------------------------------------------------------------
__global__ __launch_bounds__(256, 3)
void attn_mfma(const __half* __restrict__ qh, const __half* __restrict__ kh,
               const __half* __restrict__ vh, unsigned short* __restrict__ ob) {
  __shared__ __align__(16) __half Ks[2][4096];  // [krow][d] 64x64, swizzled
  __shared__ __align__(16) __half Vs[2][4096];  // [d][krow] 64x64, swizzled
  __shared__ __align__(16) __half Pl[8][1152];  // [wave*2+g][16 x 72]
  const int t = threadIdx.x;
  const int w = t >> 6, lane = t & 63;
  const int flat = blockIdx.x + blockIdx.y * 8;  // grid (8, 128)
  const int xcd = flat & 7, j = flat >> 3;       // j in [0,128)
  const int bh = xcd * 16 + (j >> 3);            // 16 heads per XCD
  const int qt = j & 7;                          // 128-row Q tile
  const int lm = lane & 15, q4 = lane >> 4;

  f16x8 qf[2][2];
#pragma unroll
  for (int g = 0; g < 2; ++g) {
    const __half* qrow =
        qh + ((long)(bh * 1024 + qt * 128 + g * 64 + w * 16 + lm)) * 64 +
        q4 * 8;
    qf[g][0] = *(const f16x8*)qrow;
    qf[g][1] = *(const f16x8*)(qrow + 32);
  }

  f32x4 o[2][4] = {};
  float l_r[2][4] = {};

  const int prow = t >> 3, pc = t & 7;
  const int scz = pc ^ (prow & 7);  // swizzled source chunk
  const __half* ksrc0 = kh + (long)(bh * 1024 + prow) * 64 + scz * 8;
  const __half* vsrc0 = vh + (long)(bh * 64 + prow) * 1024 + scz * 8;

  gload16(ksrc0, &Ks[0][t * 8]);
  gload16(ksrc0 + 32 * 64, &Ks[0][2048 + t * 8]);
  gload16(vsrc0, &Vs[0][t * 8]);
  gload16(vsrc0 + 32 * 1024, &Vs[0][2048 + t * 8]);

  for (int kc = 0; kc < 16; ++kc) {
    const int cur = kc & 1;
    __syncthreads();

    if (kc < 15) {
      const int nx = cur ^ 1;
      const __half* ksrc = ksrc0 + (kc + 1) * 4096;
      const __half* vsrc = vsrc0 + (kc + 1) * 64;
      gload16(ksrc, &Ks[nx][t * 8]);
      gload16(ksrc + 32 * 64, &Ks[nx][2048 + t * 8]);
      gload16(vsrc, &Vs[nx][t * 8]);
      gload16(vsrc + 32 * 1024, &Vs[nx][2048 + t * 8]);
    }

    // K fragments once per chunk, shared by both groups
    f16x8 kf[4][2];
#pragma unroll
    for (int nt = 0; nt < 4; ++nt) {
      const int kr = nt * 16 + lm;
#pragma unroll
      for (int ks = 0; ks < 2; ++ks)
        kf[nt][ks] = *(const f16x8*)&Ks[cur][kr * 64 +
                                      (((ks << 2) + q4) ^ (kr & 7)) * 8];
    }

    // S = Q K^T per group; softmax into per-group P strip
#pragma unroll
    for (int g = 0; g < 2; ++g) {
      f32x4 s[4];
      __builtin_amdgcn_s_setprio(1);
#pragma unroll
      for (int nt = 0; nt < 4; ++nt) {
        s[nt] = (f32x4){0.f, 0.f, 0.f, 0.f};
#pragma unroll
        for (int ks = 0; ks < 2; ++ks)
          s[nt] = __builtin_amdgcn_mfma_f32_16x16x32_f16(qf[g][ks], kf[nt][ks],
                                                         s[nt], 0, 0, 0);
      }
      __builtin_amdgcn_s_setprio(0);
      __half* Pw = &Pl[w * 2 + g][0];
#pragma unroll
      for (int nt = 0; nt < 4; ++nt) {
#pragma unroll
        for (int r = 0; r < 4; ++r) {
          const float p = exp2f(s[nt][r] - 12.98425536800067f);  // 9*log2(e)
          l_r[g][r] += p;
          Pw[(q4 * 4 + r) * 72 + nt * 16 + lm] = (__half)p;
        }
      }
    }

    // O += P V: V fragment read once, feeds both groups
    __builtin_amdgcn_s_setprio(1);
#pragma unroll
    for (int ks2 = 0; ks2 < 2; ++ks2) {
      const f16x8 pf0 = *(const f16x8*)&Pl[w * 2 + 0][lm * 72 + ks2 * 32 +
                                                      q4 * 8];
      const f16x8 pf1 = *(const f16x8*)&Pl[w * 2 + 1][lm * 72 + ks2 * 32 +
                                                      q4 * 8];
#pragma unroll
      for (int nt = 0; nt < 4; ++nt) {
        const int dr = nt * 16 + lm;
        const f16x8 vf = *(const f16x8*)&Vs[cur][dr * 64 +
                                          (((ks2 << 2) + q4) ^ (dr & 7)) * 8];
        o[0][nt] = __builtin_amdgcn_mfma_f32_16x16x32_f16(pf0, vf, o[0][nt],
                                                          0, 0, 0);
        o[1][nt] = __builtin_amdgcn_mfma_f32_16x16x32_f16(pf1, vf, o[1][nt],
                                                          0, 0, 0);
      }
    }
    __builtin_amdgcn_s_setprio(0);
  }

  const int b = bh >> 4, h = bh & 15;
#pragma unroll
  for (int g = 0; g < 2; ++g) {
#pragma unroll
    for (int r = 0; r < 4; ++r) {
      float l = l_r[g][r];
      l += __shfl_xor(l, 1, 64);
      l += __shfl_xor(l, 2, 64);
      l += __shfl_xor(l, 4, 64);
      l += __shfl_xor(l, 8, 64);
      const float linv = 1.0f / l;
      const long rowg =
          (long)(b * 1024 + qt * 128 + g * 64 + w * 16 + q4 * 4 + r) * 1024 +
          h * 64;
#pragma unroll
      for (int nt = 0; nt < 4; ++nt)
        ob[rowg + nt * 16 + lm] = f2bf(o[g][nt][r] * linv);
    }
  }
}

extern "C" void kernel_launch(void* const* d_in, const int* in_sizes, int n_in,
                              void* d_out, int out_size, void* d_ws,
                              size_t ws_size, hipStream_t stream) {
  const float* x    = (const float*)d_in[0];
  const float* Wqkv = (const float*)d_in[1];
  const float* bqkv = (const float*)d_in[2];
  const float* Wout = (const float*)d_in[3];
  const float* bout = (const float*)d_in[4];
  const float* qs   = (const float*)d_in[5];
  const float* ks   = (const float*)d_in[6];
  float* out = (float*)d_out;
  float* W = (float*)d_ws;  // 72 MB

  __half* qkvh = (__half*)W;            // q:0  k:+QSZ  vT:+2*QSZ (halfs)
  __half* qpre = qkvh;
  __half* kpre = qkvh + QSZ;
  __half* vT   = qkvh + 2 * QSZ;
  unsigned short* xb  = (unsigned short*)(W + 12582912);
  unsigned short* ob  = xb;
  unsigned short* wqT = (unsigned short*)(W + 16777216);
  unsigned short* woT = wqT + 3 * 1024 * 1024;

  cvt_bf16<<<4096, 256, 0, stream>>>(x, xb);
  cvt_t<<<dim3(96, 32), 256, 0, stream>>>(Wqkv, wqT, 3072);
  cvt_t<<<dim3(32, 32), 256, 0, stream>>>(Wout, woT, 1024);
  // 1) QKV projection + fused RMSNorm/RoPE (256^2 counted-vmcnt pipeline)
  gemm256<0><<<384, 512, 0, stream>>>(xb, wqT, bqkv, nullptr, qkvh, qs, ks);
  // 2) MFMA flash attention (128-row blocks) -> ob bf16 row-major
  attn_mfma<<<dim3(8, 128), 256, 0, stream>>>(qpre, kpre, vT, ob);
  // 3) output projection (same 256^2 structure; grid 128 = single round)
  gemm256<1><<<128, 512, 0, stream>>>(ob, woT, bout, out, nullptr, nullptr,
                                      nullptr);
}

// Round 7
// 265.140 us; speedup vs baseline: 1.0406x; 1.0113x over previous
//
#include <hip/hip_runtime.h>
#include <hip/hip_bf16.h>
#include <hip/hip_fp16.h>
#include <math.h>

// B=8, H=16, N=1024, D=1024, hd=64
// ws layout (float units):
//   qpre f16 (B,H,N,64)   [0, 4M)        8M halfs   (normed+roped by gemm)
//   kpre f16 (B,H,N,64)   [4M, 8M)
//   vT   f16 (B,H,64,N)   [8M, 12M)      transposed per head
//   xb   bf16 [12M,16M)   (reused as ob after QKV gemm)
//   wqT  bf16 [16M,17.5M) ; woT bf16 [17.5M,18M)
// total 72 MB
#define QSZ 8388608  // halfs per q/k/v region

typedef short bf16x8 __attribute__((ext_vector_type(8)));
typedef _Float16 f16x8 __attribute__((ext_vector_type(8)));
typedef float f32x4 __attribute__((ext_vector_type(4)));

__device__ __forceinline__ unsigned short f2bf(float f) {
  __hip_bfloat16 h = __float2bfloat16(f);
  return *reinterpret_cast<unsigned short*>(&h);
}

__device__ __forceinline__ void gload16(const void* g, void* l) {
  __builtin_amdgcn_global_load_lds(
      (const __attribute__((address_space(1))) void*)g,
      (__attribute__((address_space(3))) void*)l, 16, 0, 0);
}

// ---------------------------------------------------------------------------
// merged conversion pass (one dispatch, 8192 blocks):
//   [0,4096)     x fp32 -> xb bf16 (elementwise)
//   [4096,7168)  Wqkv [1024,3072] fp32 -> wqT [3072,1024] bf16 (transpose)
//   [7168,8192)  Wout [1024,1024] fp32 -> woT [1024,1024] bf16 (transpose)
// ---------------------------------------------------------------------------
__global__ __launch_bounds__(256)
void cvt_all(const float* __restrict__ x, unsigned short* __restrict__ xb,
             const float* __restrict__ Wq, unsigned short* __restrict__ wqT,
             const float* __restrict__ Wo, unsigned short* __restrict__ woT) {
  __shared__ unsigned short tile[32][33];
  const int bid = blockIdx.x;
  const int t = threadIdx.x;
  if (bid < 4096) {
    const int i = (bid * 256 + t) * 8;
    const float4 a = *(const float4*)&x[i];
    const float4 b = *(const float4*)&x[i + 4];
    ushort4 lo, hi;
    lo.x = f2bf(a.x); lo.y = f2bf(a.y); lo.z = f2bf(a.z); lo.w = f2bf(a.w);
    hi.x = f2bf(b.x); hi.y = f2bf(b.y); hi.z = f2bf(b.z); hi.w = f2bf(b.w);
    *(ushort4*)&xb[i] = lo;
    *(ushort4*)&xb[i + 4] = hi;
    return;
  }
  const float* src;
  unsigned short* dst;
  int bx, by, N;
  if (bid < 7168) {
    src = Wq; dst = wqT; N = 3072;
    bx = (bid - 4096) % 96; by = (bid - 4096) / 96;
  } else {
    src = Wo; dst = woT; N = 1024;
    bx = (bid - 7168) % 32; by = (bid - 7168) / 32;
  }
  const int k0 = by * 32, n0 = bx * 32;
  const int r = t >> 3, c4 = (t & 7) * 4;
  const float4 v = *(const float4*)&src[(k0 + r) * N + n0 + c4];
  tile[r][c4 + 0] = f2bf(v.x);
  tile[r][c4 + 1] = f2bf(v.y);
  tile[r][c4 + 2] = f2bf(v.z);
  tile[r][c4 + 3] = f2bf(v.w);
  __syncthreads();
  ushort4 o;
  o.x = tile[c4 + 0][r];
  o.y = tile[c4 + 1][r];
  o.z = tile[c4 + 2][r];
  o.w = tile[c4 + 3][r];
  *(ushort4*)&dst[(long)(n0 + r) * 1024 + k0 + c4] = o;
}

// ---------------------------------------------------------------------------
// 256x256-tile counted-vmcnt deep-pipeline bf16 GEMM (R5-proven config:
// BK=64, bounds (512,2) -- (512,4) forces acc spill on the unified
// VGPR/AGPR file and must not be used; 4-phase and BK=32 variants measured
// or reasoned slower):
//   - 512 threads = 8 waves (2M x 4N), per-wave 128x64 output, BK=64
//   - LDS: 2 x (256x64) A + 2 x (256x64) B; 128-B rows with 3-bit XOR
//     swizzle (chunk ^= row&7), inverse-swizzled global source +
//     swizzled ds_read. Conflicts measured ~184K.
//   - raw s_barrier + manual s_waitcnt; vmcnt(8) steady state (tile t+2's
//     8 loads stay in flight across both barriers; never drained to 0)
// MODE 0 (QKV, grid 384 = 32bm x 12bn): fused RMSNorm + 2D-RoPE epilogue;
//   q/k f16 (B,H,N,64), v f16 transposed (B,H,64,N). Wave col-span = 1 head.
//   q pre-scaled by hd^-0.5 * log2(e) so attention softmax is a bare exp2.
// MODE 1 (out-proj, grid 128 = 32bm x 4bn): fp32 row-major + bias.
// ---------------------------------------------------------------------------
template<int MODE>
__global__ __launch_bounds__(512, 2)
void gemm256(const unsigned short* __restrict__ A,
             const unsigned short* __restrict__ Bt,
             const float* __restrict__ bias,
             float* __restrict__ Cf,
             __half* __restrict__ Ch,
             const float* __restrict__ qsc,
             const float* __restrict__ ksc) {
  __shared__ __align__(16) unsigned short As[2][16384];
  __shared__ __align__(16) unsigned short Bs[2][16384];
  __shared__ float2 Tab[512];  // [pos 0..31][idx 0..15] cos/sin (MODE 0)

  constexpr int GXN = (MODE == 0) ? 12 : 4;   // bn tiles
  constexpr int CPX = (MODE == 0) ? 48 : 16;  // blocks per XCD (nwg/8)

  const int t = threadIdx.x;
  // bijective XCD swizzle (nwg % 8 == 0)
  const int swz = (blockIdx.x & 7) * CPX + (blockIdx.x >> 3);
  const int bm = swz / GXN, bn = swz % GXN;
  const int w = t >> 6, lane = t & 63;
  const int M0 = (w >> 2) * 128, N0 = (w & 3) * 64;
  const int lm = lane & 15, q4 = lane >> 4;

  if (MODE == 0) {  // RoPE table (visible after prologue barrier)
    const int pos = t >> 4, idx = t & 15;
    const float invf = expf(-(float)idx * 0.57564627324851149f);
    const float ang = (float)pos * invf;
    Tab[t] = make_float2(cosf(ang), sinf(ang));
  }

  // staging: thread t writes LDS row (j*64 + t>>3), 16B chunk (t&7).
  // inverse swizzle on the global source so swizzled reads see logical data.
  const int c8 = ((t & 7) ^ ((t >> 3) & 7)) << 3;
  const unsigned short* aSrc = A + (long)(bm * 256 + (t >> 3)) * 1024 + c8;
  const unsigned short* bSrc = Bt + (long)(bn * 256 + (t >> 3)) * 1024 + c8;
  unsigned short* lA[2] = {&As[0][t * 8], &As[1][t * 8]};
  unsigned short* lB[2] = {&Bs[0][t * 8], &Bs[1][t * 8]};

  f32x4 acc[8][4] = {};

  auto stage = [&](int buf, int kt) {  // 8 gload_lds per thread = one K-tile
    const unsigned short* a = aSrc + kt * 64;
    const unsigned short* b = bSrc + kt * 64;
    unsigned short* la = lA[buf];
    unsigned short* lb = lB[buf];
#pragma unroll
    for (int j = 0; j < 4; ++j) {
      gload16(a + j * 65536, la + j * 4096);
      gload16(b + j * 65536, lb + j * 4096);
    }
  };

  auto compute = [&](const unsigned short* Ac, const unsigned short* Bc) {
#pragma unroll
    for (int kk = 0; kk < 2; ++kk) {
      bf16x8 af[8], bg[4];
#pragma unroll
      for (int mi = 0; mi < 8; ++mi) {
        const int row = M0 + mi * 16 + lm;
        af[mi] = *(const bf16x8*)
            &Ac[row * 64 + ((((kk << 2) + q4) ^ (row & 7)) << 3)];
      }
#pragma unroll
      for (int ni = 0; ni < 4; ++ni) {
        const int row = N0 + ni * 16 + lm;
        bg[ni] = *(const bf16x8*)
            &Bc[row * 64 + ((((kk << 2) + q4) ^ (row & 7)) << 3)];
      }
#pragma unroll
      for (int mi = 0; mi < 8; ++mi)
#pragma unroll
        for (int ni = 0; ni < 4; ++ni)
          acc[mi][ni] = __builtin_amdgcn_mfma_f32_16x16x32_bf16(
              af[mi], bg[ni], acc[mi][ni], 0, 0, 0);
    }
  };

  // prologue: tiles 0,1 in flight; wait tile 0 (vmcnt: 16 out -> 8 = tile1)
  stage(0, 0);
  stage(1, 1);
  asm volatile("s_waitcnt vmcnt(8)" ::: "memory");
  __builtin_amdgcn_s_barrier();

  // steady state: compute tile kt from buf[s]; after all waves finished
  // reading buf[s] (lgkmcnt(0) + barrier), issue tile kt+2 into buf[s];
  // vmcnt(8) retires exactly tile kt+1's loads; 8 loads cross the barrier.
  for (int kt = 0; kt < 14; ++kt) {
    const int s = kt & 1;
    compute(s ? &As[1][0] : &As[0][0], s ? &Bs[1][0] : &Bs[0][0]);
    asm volatile("s_waitcnt lgkmcnt(0)" ::: "memory");
    __builtin_amdgcn_s_barrier();
    stage(s, kt + 2);
    asm volatile("s_waitcnt vmcnt(8)" ::: "memory");
    __builtin_amdgcn_s_barrier();
  }
  compute(&As[0][0], &Bs[0][0]);
  asm volatile("s_waitcnt lgkmcnt(0)" ::: "memory");
  __builtin_amdgcn_s_barrier();
  asm volatile("s_waitcnt vmcnt(0)" ::: "memory");
  __builtin_amdgcn_s_barrier();
  compute(&As[1][0], &Bs[1][0]);

  // ---- epilogues ----
  const int r0 = q4 << 2;
  const int nb = bn * 256 + N0;

  if (MODE == 1) {  // out-proj: fp32 row-major + bias
#pragma unroll
    for (int mi = 0; mi < 8; ++mi)
#pragma unroll
      for (int ni = 0; ni < 4; ++ni) {
        const int n = nb + ni * 16 + lm;
        const float bvv = bias[n];
#pragma unroll
        for (int r = 0; r < 4; ++r)
          Cf[(long)(bm * 256 + M0 + mi * 16 + r0 + r) * 1024 + n] =
              acc[mi][ni][r] + bvv;
      }
    return;
  }

  // MODE 0 fused epilogue (wave col-span = one head)
  const int tq = nb >> 10, h = (nb >> 6) & 15;

  if (tq == 2) {  // v: f16 transpose-scatter (B,H,64,N)
#pragma unroll
    for (int mi = 0; mi < 8; ++mi)
#pragma unroll
      for (int ni = 0; ni < 4; ++ni) {
        const int col = nb + ni * 16 + lm;
        const int dd = col & 63;
        const float bv = bias[col];
#pragma unroll
        for (int r = 0; r < 4; ++r) {
          const int m = bm * 256 + M0 + mi * 16 + r0 + r;
          const int b = m >> 10, nn = m & 1023;
          Ch[2L * QSZ + ((long)((b * 16 + h) * 64 + dd)) * 1024 + nn] =
              __float2half(acc[mi][ni][r] + bv);
        }
      }
    return;
  }

  // q or k: RMSNorm + RoPE on f32 accs, then f16 store (B,H,N,64)
  const float* scp = (tq == 0) ? qsc : ksc;
  // q: fold hd^-0.5 AND log2(e) (softmax uses exp2) into the stored q
  const float qmul = (tq == 0) ? 0.18033688011112042f : 1.0f;
  float scv[4], bv[4];
#pragma unroll
  for (int ni = 0; ni < 4; ++ni) {
    scv[ni] = scp[ni * 16 + lm];
    bv[ni] = bias[nb + ni * 16 + lm];
  }
  __half* base = Ch + (long)tq * QSZ;
#pragma unroll
  for (int mi = 0; mi < 8; ++mi) {
#pragma unroll
    for (int r = 0; r < 4; ++r) {
      const float v0 = acc[mi][0][r] + bv[0];
      const float v1 = acc[mi][1][r] + bv[1];
      const float v2 = acc[mi][2][r] + bv[2];
      const float v3 = acc[mi][3][r] + bv[3];
      float ss = v0 * v0 + v1 * v1 + v2 * v2 + v3 * v3;
      ss += __shfl_xor(ss, 1, 64);
      ss += __shfl_xor(ss, 2, 64);
      ss += __shfl_xor(ss, 4, 64);
      ss += __shfl_xor(ss, 8, 64);
      const float inv = rsqrtf(ss * (1.0f / 64.0f) + 1e-6f) * qmul;
      const float a0 = v0 * inv * scv[0];
      const float a1 = v1 * inv * scv[1];
      const float a2 = v2 * inv * scv[2];
      const float a3 = v3 * inv * scv[3];
      const int m = bm * 256 + M0 + mi * 16 + r0 + r;
      const int b = m >> 10, nn = m & 1023;
      const float2 tr = Tab[(nn >> 5) * 16 + lm];  // row-part angles
      const float2 tc = Tab[(nn & 31) * 16 + lm];  // col-part angles
      __half* row = base + ((long)((b * 16 + h) * 1024 + nn)) * 64 + lm;
      row[0]  = __float2half(a0 * tr.x - a2 * tr.y);
      row[16] = __float2half(a1 * tc.x - a3 * tc.y);
      row[32] = __float2half(a0 * tr.y + a2 * tr.x);
      row[48] = __float2half(a1 * tc.y + a3 * tc.x);
    }
  }
}

// ---------------------------------------------------------------------------
// MFMA flash attention (f16), fixed-offset softmax (exp2; log2e folded into
// q), single-barrier dbuf, 128 Q-rows per block. K/V fragments hoisted out
// of the group loop (read once per K-chunk, shared by both 16-row groups).
// ---------------------------------------------------------------------------
__global__ __launch_bounds__(256, 3)
void attn_mfma(const __half* __restrict__ qh, const __half* __restrict__ kh,
               const __half* __restrict__ vh, unsigned short* __restrict__ ob) {
  __shared__ __align__(16) __half Ks[2][4096];  // [krow][d] 64x64, swizzled
  __shared__ __align__(16) __half Vs[2][4096];  // [d][krow] 64x64, swizzled
  __shared__ __align__(16) __half Pl[8][1152];  // [wave*2+g][16 x 72]
  const int t = threadIdx.x;
  const int w = t >> 6, lane = t & 63;
  const int flat = blockIdx.x + blockIdx.y * 8;  // grid (8, 128)
  const int xcd = flat & 7, j = flat >> 3;       // j in [0,128)
  const int bh = xcd * 16 + (j >> 3);            // 16 heads per XCD
  const int qt = j & 7;                          // 128-row Q tile
  const int lm = lane & 15, q4 = lane >> 4;

  f16x8 qf[2][2];
#pragma unroll
  for (int g = 0; g < 2; ++g) {
    const __half* qrow =
        qh + ((long)(bh * 1024 + qt * 128 + g * 64 + w * 16 + lm)) * 64 +
        q4 * 8;
    qf[g][0] = *(const f16x8*)qrow;
    qf[g][1] = *(const f16x8*)(qrow + 32);
  }

  f32x4 o[2][4] = {};
  float l_r[2][4] = {};

  const int prow = t >> 3, pc = t & 7;
  const int scz = pc ^ (prow & 7);  // swizzled source chunk
  const __half* ksrc0 = kh + (long)(bh * 1024 + prow) * 64 + scz * 8;
  const __half* vsrc0 = vh + (long)(bh * 64 + prow) * 1024 + scz * 8;

  gload16(ksrc0, &Ks[0][t * 8]);
  gload16(ksrc0 + 32 * 64, &Ks[0][2048 + t * 8]);
  gload16(vsrc0, &Vs[0][t * 8]);
  gload16(vsrc0 + 32 * 1024, &Vs[0][2048 + t * 8]);

  for (int kc = 0; kc < 16; ++kc) {
    const int cur = kc & 1;
    __syncthreads();

    if (kc < 15) {
      const int nx = cur ^ 1;
      const __half* ksrc = ksrc0 + (kc + 1) * 4096;
      const __half* vsrc = vsrc0 + (kc + 1) * 64;
      gload16(ksrc, &Ks[nx][t * 8]);
      gload16(ksrc + 32 * 64, &Ks[nx][2048 + t * 8]);
      gload16(vsrc, &Vs[nx][t * 8]);
      gload16(vsrc + 32 * 1024, &Vs[nx][2048 + t * 8]);
    }

    // K fragments once per chunk, shared by both groups
    f16x8 kf[4][2];
#pragma unroll
    for (int nt = 0; nt < 4; ++nt) {
      const int kr = nt * 16 + lm;
#pragma unroll
      for (int ks = 0; ks < 2; ++ks)
        kf[nt][ks] = *(const f16x8*)&Ks[cur][kr * 64 +
                                      (((ks << 2) + q4) ^ (kr & 7)) * 8];
    }

    // S = Q K^T per group; softmax into per-group P strip
#pragma unroll
    for (int g = 0; g < 2; ++g) {
      f32x4 s[4];
      __builtin_amdgcn_s_setprio(1);
#pragma unroll
      for (int nt = 0; nt < 4; ++nt) {
        s[nt] = (f32x4){0.f, 0.f, 0.f, 0.f};
#pragma unroll
        for (int ks = 0; ks < 2; ++ks)
          s[nt] = __builtin_amdgcn_mfma_f32_16x16x32_f16(qf[g][ks], kf[nt][ks],
                                                         s[nt], 0, 0, 0);
      }
      __builtin_amdgcn_s_setprio(0);
      __half* Pw = &Pl[w * 2 + g][0];
#pragma unroll
      for (int nt = 0; nt < 4; ++nt) {
#pragma unroll
        for (int r = 0; r < 4; ++r) {
          const float p = exp2f(s[nt][r] - 12.98425536800067f);  // 9*log2(e)
          l_r[g][r] += p;
          Pw[(q4 * 4 + r) * 72 + nt * 16 + lm] = (__half)p;
        }
      }
    }

    // O += P V: V fragment read once, feeds both groups
    __builtin_amdgcn_s_setprio(1);
#pragma unroll
    for (int ks2 = 0; ks2 < 2; ++ks2) {
      const f16x8 pf0 = *(const f16x8*)&Pl[w * 2 + 0][lm * 72 + ks2 * 32 +
                                                      q4 * 8];
      const f16x8 pf1 = *(const f16x8*)&Pl[w * 2 + 1][lm * 72 + ks2 * 32 +
                                                      q4 * 8];
#pragma unroll
      for (int nt = 0; nt < 4; ++nt) {
        const int dr = nt * 16 + lm;
        const f16x8 vf = *(const f16x8*)&Vs[cur][dr * 64 +
                                          (((ks2 << 2) + q4) ^ (dr & 7)) * 8];
        o[0][nt] = __builtin_amdgcn_mfma_f32_16x16x32_f16(pf0, vf, o[0][nt],
                                                          0, 0, 0);
        o[1][nt] = __builtin_amdgcn_mfma_f32_16x16x32_f16(pf1, vf, o[1][nt],
                                                          0, 0, 0);
      }
    }
    __builtin_amdgcn_s_setprio(0);
  }

  const int b = bh >> 4, h = bh & 15;
#pragma unroll
  for (int g = 0; g < 2; ++g) {
#pragma unroll
    for (int r = 0; r < 4; ++r) {
      float l = l_r[g][r];
      l += __shfl_xor(l, 1, 64);
      l += __shfl_xor(l, 2, 64);
      l += __shfl_xor(l, 4, 64);
      l += __shfl_xor(l, 8, 64);
      const float linv = 1.0f / l;
      const long rowg =
          (long)(b * 1024 + qt * 128 + g * 64 + w * 16 + q4 * 4 + r) * 1024 +
          h * 64;
#pragma unroll
      for (int nt = 0; nt < 4; ++nt)
        ob[rowg + nt * 16 + lm] = f2bf(o[g][nt][r] * linv);
    }
  }
}

extern "C" void kernel_launch(void* const* d_in, const int* in_sizes, int n_in,
                              void* d_out, int out_size, void* d_ws,
                              size_t ws_size, hipStream_t stream) {
  const float* x    = (const float*)d_in[0];
  const float* Wqkv = (const float*)d_in[1];
  const float* bqkv = (const float*)d_in[2];
  const float* Wout = (const float*)d_in[3];
  const float* bout = (const float*)d_in[4];
  const float* qs   = (const float*)d_in[5];
  const float* ks   = (const float*)d_in[6];
  float* out = (float*)d_out;
  float* W = (float*)d_ws;  // 72 MB

  __half* qkvh = (__half*)W;            // q:0  k:+QSZ  vT:+2*QSZ (halfs)
  __half* qpre = qkvh;
  __half* kpre = qkvh + QSZ;
  __half* vT   = qkvh + 2 * QSZ;
  unsigned short* xb  = (unsigned short*)(W + 12582912);
  unsigned short* ob  = xb;
  unsigned short* wqT = (unsigned short*)(W + 16777216);
  unsigned short* woT = wqT + 3 * 1024 * 1024;

  // 0) all input conversions in one dispatch
  cvt_all<<<8192, 256, 0, stream>>>(x, xb, Wqkv, wqT, Wout, woT);
  // 1) QKV projection + fused RMSNorm/RoPE (256^2 counted-vmcnt pipeline)
  gemm256<0><<<384, 512, 0, stream>>>(xb, wqT, bqkv, nullptr, qkvh, qs, ks);
  // 2) MFMA flash attention (128-row blocks) -> ob bf16 row-major
  attn_mfma<<<dim3(8, 128), 256, 0, stream>>>(qpre, kpre, vT, ob);
  // 3) output projection (same 256^2 structure; grid 128)
  gemm256<1><<<128, 512, 0, stream>>>(ob, woT, bout, out, nullptr, nullptr,
                                      nullptr);
}

// Round 8
// 252.858 us; speedup vs baseline: 1.0911x; 1.0486x over previous
//
#include <hip/hip_runtime.h>
#include <hip/hip_bf16.h>
#include <hip/hip_fp16.h>
#include <math.h>

// B=8, H=16, N=1024, D=1024, hd=64
// ws layout (float units):
//   qpre f16 (B,H,N,64)   [0, 4M)        8M halfs   (normed+roped by gemm)
//   kpre f16 (B,H,N,64)   [4M, 8M)
//   vT   f16 (B,H,64,N)   [8M, 12M)      transposed per head
//   xb   bf16 [12M,16M)   (reused as ob after QKV gemm)
//   wqT  bf16 [16M,17.5M) ; woT bf16 [17.5M,18M)
// total 72 MB
#define QSZ 8388608  // halfs per q/k/v region

typedef short bf16x8 __attribute__((ext_vector_type(8)));
typedef _Float16 f16x8 __attribute__((ext_vector_type(8)));
typedef _Float16 f16x4 __attribute__((ext_vector_type(4)));
typedef float f32x4 __attribute__((ext_vector_type(4)));

__device__ __forceinline__ unsigned short f2bf(float f) {
  __hip_bfloat16 h = __float2bfloat16(f);
  return *reinterpret_cast<unsigned short*>(&h);
}

__device__ __forceinline__ void gload16(const void* g, void* l) {
  __builtin_amdgcn_global_load_lds(
      (const __attribute__((address_space(1))) void*)g,
      (__attribute__((address_space(3))) void*)l, 16, 0, 0);
}

// ---------------------------------------------------------------------------
// merged conversion pass (one dispatch, 8192 blocks):
//   [0,4096)     x fp32 -> xb bf16 (elementwise)
//   [4096,7168)  Wqkv [1024,3072] fp32 -> wqT [3072,1024] bf16 (transpose)
//   [7168,8192)  Wout [1024,1024] fp32 -> woT [1024,1024] bf16 (transpose)
// ---------------------------------------------------------------------------
__global__ __launch_bounds__(256)
void cvt_all(const float* __restrict__ x, unsigned short* __restrict__ xb,
             const float* __restrict__ Wq, unsigned short* __restrict__ wqT,
             const float* __restrict__ Wo, unsigned short* __restrict__ woT) {
  __shared__ unsigned short tile[32][33];
  const int bid = blockIdx.x;
  const int t = threadIdx.x;
  if (bid < 4096) {
    const int i = (bid * 256 + t) * 8;
    const float4 a = *(const float4*)&x[i];
    const float4 b = *(const float4*)&x[i + 4];
    ushort4 lo, hi;
    lo.x = f2bf(a.x); lo.y = f2bf(a.y); lo.z = f2bf(a.z); lo.w = f2bf(a.w);
    hi.x = f2bf(b.x); hi.y = f2bf(b.y); hi.z = f2bf(b.z); hi.w = f2bf(b.w);
    *(ushort4*)&xb[i] = lo;
    *(ushort4*)&xb[i + 4] = hi;
    return;
  }
  const float* src;
  unsigned short* dst;
  int bx, by, N;
  if (bid < 7168) {
    src = Wq; dst = wqT; N = 3072;
    bx = (bid - 4096) % 96; by = (bid - 4096) / 96;
  } else {
    src = Wo; dst = woT; N = 1024;
    bx = (bid - 7168) % 32; by = (bid - 7168) / 32;
  }
  const int k0 = by * 32, n0 = bx * 32;
  const int r = t >> 3, c4 = (t & 7) * 4;
  const float4 v = *(const float4*)&src[(k0 + r) * N + n0 + c4];
  tile[r][c4 + 0] = f2bf(v.x);
  tile[r][c4 + 1] = f2bf(v.y);
  tile[r][c4 + 2] = f2bf(v.z);
  tile[r][c4 + 3] = f2bf(v.w);
  __syncthreads();
  ushort4 o;
  o.x = tile[c4 + 0][r];
  o.y = tile[c4 + 1][r];
  o.z = tile[c4 + 2][r];
  o.w = tile[c4 + 3][r];
  *(ushort4*)&dst[(long)(n0 + r) * 1024 + k0 + c4] = o;
}

// ---------------------------------------------------------------------------
// counted-vmcnt deep-pipeline bf16 GEMM (R5-proven schedule; bounds (512,2)
// mandatory -- (512,4) spills the unified-file accumulator):
//   - 512 threads = 8 waves (2M x 4N), BK=64
//   - 128-B rows with 3-bit XOR swizzle (chunk ^= row&7), inverse-swizzled
//     global source + swizzled ds_read. Conflicts measured ~184K.
//   - raw s_barrier + manual s_waitcnt; vmcnt(LOADS) steady state (tile
//     t+2's loads stay in flight across both barriers; never drained to 0)
// MODE 0 (QKV): BM=256, BN=256, per-wave 128x64, grid 384 = 32bm x 12bn.
//   Fused RMSNorm + 2D-RoPE epilogue; q/k f16 (B,H,N,64), v f16 transposed
//   (B,H,64,N). Wave col-span = 1 head. q pre-scaled by hd^-0.5 * log2(e).
// MODE 1 (out-proj): BM=128, BN=256, per-wave 64x64, grid 256 = 64bm x 4bn
//   -> one full dispatch round on 256 CUs (the old 128-block grid left half
//   the machine idle). fp32 row-major + bias epilogue.
// ---------------------------------------------------------------------------
template<int MODE>
__global__ __launch_bounds__(512, 2)
void gemm256(const unsigned short* __restrict__ A,
             const unsigned short* __restrict__ Bt,
             const float* __restrict__ bias,
             float* __restrict__ Cf,
             __half* __restrict__ Ch,
             const float* __restrict__ qsc,
             const float* __restrict__ ksc) {
  constexpr int BM  = (MODE == 0) ? 256 : 128;  // M-tile
  constexpr int AM  = (MODE == 0) ? 8 : 4;      // acc rows (per-wave M/16)
  constexpr int LA  = BM / 64;                  // A gloads per thread
  constexpr int GXN = (MODE == 0) ? 12 : 4;     // bn tiles
  constexpr int CPX = (MODE == 0) ? 48 : 32;    // blocks per XCD (nwg/8)

  __shared__ __align__(16) unsigned short As[2][BM * 64];
  __shared__ __align__(16) unsigned short Bs[2][16384];
  __shared__ float2 Tab[512];  // [pos 0..31][idx 0..15] cos/sin (MODE 0)

  const int t = threadIdx.x;
  // bijective XCD swizzle (nwg % 8 == 0)
  const int swz = (blockIdx.x & 7) * CPX + (blockIdx.x >> 3);
  const int bm = swz / GXN, bn = swz % GXN;
  const int w = t >> 6, lane = t & 63;
  const int M0 = (w >> 2) * (BM / 2), N0 = (w & 3) * 64;
  const int lm = lane & 15, q4 = lane >> 4;

  if (MODE == 0) {  // RoPE table (visible after prologue barrier)
    const int pos = t >> 4, idx = t & 15;
    const float invf = expf(-(float)idx * 0.57564627324851149f);
    const float ang = (float)pos * invf;
    Tab[t] = make_float2(cosf(ang), sinf(ang));
  }

  // staging: thread t writes LDS row (j*64 + t>>3), 16B chunk (t&7).
  // inverse swizzle on the global source so swizzled reads see logical data.
  const int c8 = ((t & 7) ^ ((t >> 3) & 7)) << 3;
  const unsigned short* aSrc = A + (long)(bm * BM + (t >> 3)) * 1024 + c8;
  const unsigned short* bSrc = Bt + (long)(bn * 256 + (t >> 3)) * 1024 + c8;

  f32x4 acc[AM][4] = {};

  auto stage = [&](int buf, int kt) {  // LA+4 gload_lds per thread = 1 K-tile
    const unsigned short* a = aSrc + kt * 64;
    const unsigned short* b = bSrc + kt * 64;
#pragma unroll
    for (int j = 0; j < LA; ++j)
      gload16(a + j * 65536, &As[buf][t * 8 + j * 4096]);
#pragma unroll
    for (int j = 0; j < 4; ++j)
      gload16(b + j * 65536, &Bs[buf][t * 8 + j * 4096]);
  };
  auto waitTile = [] {  // retire down to one tile's loads in flight
    if constexpr (MODE == 0)
      asm volatile("s_waitcnt vmcnt(8)" ::: "memory");
    else
      asm volatile("s_waitcnt vmcnt(6)" ::: "memory");
  };

  auto compute = [&](const unsigned short* Ac, const unsigned short* Bc) {
#pragma unroll
    for (int kk = 0; kk < 2; ++kk) {
      bf16x8 af[AM], bg[4];
#pragma unroll
      for (int mi = 0; mi < AM; ++mi) {
        const int row = M0 + mi * 16 + lm;
        af[mi] = *(const bf16x8*)
            &Ac[row * 64 + ((((kk << 2) + q4) ^ (row & 7)) << 3)];
      }
#pragma unroll
      for (int ni = 0; ni < 4; ++ni) {
        const int row = N0 + ni * 16 + lm;
        bg[ni] = *(const bf16x8*)
            &Bc[row * 64 + ((((kk << 2) + q4) ^ (row & 7)) << 3)];
      }
#pragma unroll
      for (int mi = 0; mi < AM; ++mi)
#pragma unroll
        for (int ni = 0; ni < 4; ++ni)
          acc[mi][ni] = __builtin_amdgcn_mfma_f32_16x16x32_bf16(
              af[mi], bg[ni], acc[mi][ni], 0, 0, 0);
    }
  };

  // prologue: tiles 0,1 in flight; wait tile 0
  stage(0, 0);
  stage(1, 1);
  waitTile();
  __builtin_amdgcn_s_barrier();

  // steady state: compute tile kt from buf[s]; after all waves finished
  // reading buf[s] (lgkmcnt(0) + barrier), issue tile kt+2 into buf[s];
  // waitTile retires exactly tile kt+1's loads (kt+2's cross the barrier).
  for (int kt = 0; kt < 14; ++kt) {
    const int s = kt & 1;
    compute(s ? &As[1][0] : &As[0][0], s ? &Bs[1][0] : &Bs[0][0]);
    asm volatile("s_waitcnt lgkmcnt(0)" ::: "memory");
    __builtin_amdgcn_s_barrier();
    stage(s, kt + 2);
    waitTile();
    __builtin_amdgcn_s_barrier();
  }
  compute(&As[0][0], &Bs[0][0]);
  asm volatile("s_waitcnt lgkmcnt(0)" ::: "memory");
  __builtin_amdgcn_s_barrier();
  asm volatile("s_waitcnt vmcnt(0)" ::: "memory");
  __builtin_amdgcn_s_barrier();
  compute(&As[1][0], &Bs[1][0]);

  // ---- epilogues ----
  const int r0 = q4 << 2;
  const int nb = bn * 256 + N0;

  if (MODE == 1) {  // out-proj: fp32 row-major + bias
#pragma unroll
    for (int mi = 0; mi < AM; ++mi)
#pragma unroll
      for (int ni = 0; ni < 4; ++ni) {
        const int n = nb + ni * 16 + lm;
        const float bvv = bias[n];
#pragma unroll
        for (int r = 0; r < 4; ++r)
          Cf[(long)(bm * BM + M0 + mi * 16 + r0 + r) * 1024 + n] =
              acc[mi][ni][r] + bvv;
      }
    return;
  }

  // MODE 0 fused epilogue (wave col-span = one head)
  const int tq = nb >> 10, h = (nb >> 6) & 15;

  if (tq == 2) {  // v: f16 transpose-scatter (B,H,64,N)
#pragma unroll
    for (int mi = 0; mi < AM; ++mi)
#pragma unroll
      for (int ni = 0; ni < 4; ++ni) {
        const int col = nb + ni * 16 + lm;
        const int dd = col & 63;
        const float bv = bias[col];
#pragma unroll
        for (int r = 0; r < 4; ++r) {
          const int m = bm * BM + M0 + mi * 16 + r0 + r;
          const int b = m >> 10, nn = m & 1023;
          Ch[2L * QSZ + ((long)((b * 16 + h) * 64 + dd)) * 1024 + nn] =
              __float2half(acc[mi][ni][r] + bv);
        }
      }
    return;
  }

  // q or k: RMSNorm + RoPE on f32 accs, then f16 store (B,H,N,64)
  const float* scp = (tq == 0) ? qsc : ksc;
  // q: fold hd^-0.5 AND log2(e) (softmax uses exp2) into the stored q
  const float qmul = (tq == 0) ? 0.18033688011112042f : 1.0f;
  float scv[4], bv[4];
#pragma unroll
  for (int ni = 0; ni < 4; ++ni) {
    scv[ni] = scp[ni * 16 + lm];
    bv[ni] = bias[nb + ni * 16 + lm];
  }
  __half* base = Ch + (long)tq * QSZ;
#pragma unroll
  for (int mi = 0; mi < AM; ++mi) {
#pragma unroll
    for (int r = 0; r < 4; ++r) {
      const float v0 = acc[mi][0][r] + bv[0];
      const float v1 = acc[mi][1][r] + bv[1];
      const float v2 = acc[mi][2][r] + bv[2];
      const float v3 = acc[mi][3][r] + bv[3];
      float ss = v0 * v0 + v1 * v1 + v2 * v2 + v3 * v3;
      ss += __shfl_xor(ss, 1, 64);
      ss += __shfl_xor(ss, 2, 64);
      ss += __shfl_xor(ss, 4, 64);
      ss += __shfl_xor(ss, 8, 64);
      const float inv = rsqrtf(ss * (1.0f / 64.0f) + 1e-6f) * qmul;
      const float a0 = v0 * inv * scv[0];
      const float a1 = v1 * inv * scv[1];
      const float a2 = v2 * inv * scv[2];
      const float a3 = v3 * inv * scv[3];
      const int m = bm * BM + M0 + mi * 16 + r0 + r;
      const int b = m >> 10, nn = m & 1023;
      const float2 tr = Tab[(nn >> 5) * 16 + lm];  // row-part angles
      const float2 tc = Tab[(nn & 31) * 16 + lm];  // col-part angles
      __half* row = base + ((long)((b * 16 + h) * 1024 + nn)) * 64 + lm;
      row[0]  = __float2half(a0 * tr.x - a2 * tr.y);
      row[16] = __float2half(a1 * tc.x - a3 * tc.y);
      row[32] = __float2half(a0 * tr.y + a2 * tr.x);
      row[48] = __float2half(a1 * tc.y + a3 * tc.x);
    }
  }
}

// ---------------------------------------------------------------------------
// MFMA flash attention (f16), fixed-offset softmax (exp2; log2e folded into
// q), single-barrier dbuf, 128 Q-rows per block. K/V fragments hoisted
// (shared by both 16-row groups). QK^T computed SWAPPED -- mfma(K,Q) = S^T
// (A/B frag layouts identical, so the swap is layout-safe): each lane then
// holds 4 CONSECUTIVE k-cols for one q-row (= lm), so the P spill is 8x
// ds_write_b64 instead of 32x scalar b16, l is one scalar per lane reduced
// via shfl_xor(16|32), and linv is bpermute'd at the epilogue.
// ---------------------------------------------------------------------------
__global__ __launch_bounds__(256, 3)
void attn_mfma(const __half* __restrict__ qh, const __half* __restrict__ kh,
               const __half* __restrict__ vh, unsigned short* __restrict__ ob) {
  __shared__ __align__(16) __half Ks[2][4096];  // [krow][d] 64x64, swizzled
  __shared__ __align__(16) __half Vs[2][4096];  // [d][krow] 64x64, swizzled
  __shared__ __align__(16) __half Pl[8][1152];  // [wave*2+g][16 x 72]
  const int t = threadIdx.x;
  const int w = t >> 6, lane = t & 63;
  const int flat = blockIdx.x + blockIdx.y * 8;  // grid (8, 128)
  const int xcd = flat & 7, j = flat >> 3;       // j in [0,128)
  const int bh = xcd * 16 + (j >> 3);            // 16 heads per XCD
  const int qt = j & 7;                          // 128-row Q tile
  const int lm = lane & 15, q4 = lane >> 4;

  f16x8 qf[2][2];
#pragma unroll
  for (int g = 0; g < 2; ++g) {
    const __half* qrow =
        qh + ((long)(bh * 1024 + qt * 128 + g * 64 + w * 16 + lm)) * 64 +
        q4 * 8;
    qf[g][0] = *(const f16x8*)qrow;
    qf[g][1] = *(const f16x8*)(qrow + 32);
  }

  f32x4 o[2][4] = {};
  float l_r[2] = {};

  const int prow = t >> 3, pc = t & 7;
  const int scz = pc ^ (prow & 7);  // swizzled source chunk
  const __half* ksrc0 = kh + (long)(bh * 1024 + prow) * 64 + scz * 8;
  const __half* vsrc0 = vh + (long)(bh * 64 + prow) * 1024 + scz * 8;

  gload16(ksrc0, &Ks[0][t * 8]);
  gload16(ksrc0 + 32 * 64, &Ks[0][2048 + t * 8]);
  gload16(vsrc0, &Vs[0][t * 8]);
  gload16(vsrc0 + 32 * 1024, &Vs[0][2048 + t * 8]);

  for (int kc = 0; kc < 16; ++kc) {
    const int cur = kc & 1;
    __syncthreads();

    if (kc < 15) {
      const int nx = cur ^ 1;
      const __half* ksrc = ksrc0 + (kc + 1) * 4096;
      const __half* vsrc = vsrc0 + (kc + 1) * 64;
      gload16(ksrc, &Ks[nx][t * 8]);
      gload16(ksrc + 32 * 64, &Ks[nx][2048 + t * 8]);
      gload16(vsrc, &Vs[nx][t * 8]);
      gload16(vsrc + 32 * 1024, &Vs[nx][2048 + t * 8]);
    }

    // K fragments once per chunk, shared by both groups
    f16x8 kf[4][2];
#pragma unroll
    for (int nt = 0; nt < 4; ++nt) {
      const int kr = nt * 16 + lm;
#pragma unroll
      for (int ks = 0; ks < 2; ++ks)
        kf[nt][ks] = *(const f16x8*)&Ks[cur][kr * 64 +
                                      (((ks << 2) + q4) ^ (kr & 7)) * 8];
    }

    // S^T = K Q^T per group (lane: q-row = lm, k-cols = nt*16 + q4*4 + r)
#pragma unroll
    for (int g = 0; g < 2; ++g) {
      f32x4 s[4];
      __builtin_amdgcn_s_setprio(1);
#pragma unroll
      for (int nt = 0; nt < 4; ++nt) {
        s[nt] = (f32x4){0.f, 0.f, 0.f, 0.f};
#pragma unroll
        for (int ks = 0; ks < 2; ++ks)
          s[nt] = __builtin_amdgcn_mfma_f32_16x16x32_f16(kf[nt][ks], qf[g][ks],
                                                         s[nt], 0, 0, 0);
      }
      __builtin_amdgcn_s_setprio(0);
      __half* Pw = &Pl[w * 2 + g][0];
      float lacc = 0.f;
#pragma unroll
      for (int nt = 0; nt < 4; ++nt) {
        const float p0 = exp2f(s[nt][0] - 12.98425536800067f);  // 9*log2(e)
        const float p1 = exp2f(s[nt][1] - 12.98425536800067f);
        const float p2 = exp2f(s[nt][2] - 12.98425536800067f);
        const float p3 = exp2f(s[nt][3] - 12.98425536800067f);
        lacc += (p0 + p1) + (p2 + p3);
        f16x4 pv;
        pv[0] = (_Float16)p0; pv[1] = (_Float16)p1;
        pv[2] = (_Float16)p2; pv[3] = (_Float16)p3;
        *(f16x4*)&Pw[lm * 72 + nt * 16 + q4 * 4] = pv;  // one b64 write
      }
      l_r[g] += lacc;
    }

    // O += P V: V fragment read once, feeds both groups
    __builtin_amdgcn_s_setprio(1);
#pragma unroll
    for (int ks2 = 0; ks2 < 2; ++ks2) {
      const f16x8 pf0 = *(const f16x8*)&Pl[w * 2 + 0][lm * 72 + ks2 * 32 +
                                                      q4 * 8];
      const f16x8 pf1 = *(const f16x8*)&Pl[w * 2 + 1][lm * 72 + ks2 * 32 +
                                                      q4 * 8];
#pragma unroll
      for (int nt = 0; nt < 4; ++nt) {
        const int dr = nt * 16 + lm;
        const f16x8 vf = *(const f16x8*)&Vs[cur][dr * 64 +
                                          (((ks2 << 2) + q4) ^ (dr & 7)) * 8];
        o[0][nt] = __builtin_amdgcn_mfma_f32_16x16x32_f16(pf0, vf, o[0][nt],
                                                          0, 0, 0);
        o[1][nt] = __builtin_amdgcn_mfma_f32_16x16x32_f16(pf1, vf, o[1][nt],
                                                          0, 0, 0);
      }
    }
    __builtin_amdgcn_s_setprio(0);
  }

  const int b = bh >> 4, h = bh & 15;
#pragma unroll
  for (int g = 0; g < 2; ++g) {
    float l = l_r[g];                 // partial row-sum, q-row = lm
    l += __shfl_xor(l, 16, 64);       // sum across the 4 q4-lane groups
    l += __shfl_xor(l, 32, 64);
    const float linv_row = 1.0f / l;  // valid at every lane for q-row = lm
#pragma unroll
    for (int r = 0; r < 4; ++r) {
      const float linv = __shfl(linv_row, q4 * 4 + r, 64);  // O-row's qrow
      const long rowg =
          (long)(b * 1024 + qt * 128 + g * 64 + w * 16 + q4 * 4 + r) * 1024 +
          h * 64;
#pragma unroll
      for (int nt = 0; nt < 4; ++nt)
        ob[rowg + nt * 16 + lm] = f2bf(o[g][nt][r] * linv);
    }
  }
}

extern "C" void kernel_launch(void* const* d_in, const int* in_sizes, int n_in,
                              void* d_out, int out_size, void* d_ws,
                              size_t ws_size, hipStream_t stream) {
  const float* x    = (const float*)d_in[0];
  const float* Wqkv = (const float*)d_in[1];
  const float* bqkv = (const float*)d_in[2];
  const float* Wout = (const float*)d_in[3];
  const float* bout = (const float*)d_in[4];
  const float* qs   = (const float*)d_in[5];
  const float* ks   = (const float*)d_in[6];
  float* out = (float*)d_out;
  float* W = (float*)d_ws;  // 72 MB

  __half* qkvh = (__half*)W;            // q:0  k:+QSZ  vT:+2*QSZ (halfs)
  __half* qpre = qkvh;
  __half* kpre = qkvh + QSZ;
  __half* vT   = qkvh + 2 * QSZ;
  unsigned short* xb  = (unsigned short*)(W + 12582912);
  unsigned short* ob  = xb;
  unsigned short* wqT = (unsigned short*)(W + 16777216);
  unsigned short* woT = wqT + 3 * 1024 * 1024;

  // 0) all input conversions in one dispatch
  cvt_all<<<8192, 256, 0, stream>>>(x, xb, Wqkv, wqT, Wout, woT);
  // 1) QKV projection + fused RMSNorm/RoPE (256^2 counted-vmcnt pipeline)
  gemm256<0><<<384, 512, 0, stream>>>(xb, wqT, bqkv, nullptr, qkvh, qs, ks);
  // 2) MFMA flash attention (128-row blocks) -> ob bf16 row-major
  attn_mfma<<<dim3(8, 128), 256, 0, stream>>>(qpre, kpre, vT, ob);
  // 3) output projection (128x256 tiles; grid 256 = one full round)
  gemm256<1><<<256, 512, 0, stream>>>(ob, woT, bout, out, nullptr, nullptr,
                                      nullptr);
}

// Round 9
// 247.707 us; speedup vs baseline: 1.1138x; 1.0208x over previous
//
#include <hip/hip_runtime.h>
#include <hip/hip_bf16.h>
#include <hip/hip_fp16.h>
#include <math.h>

// B=8, H=16, N=1024, D=1024, hd=64
// ws layout (float units):
//   qpre f16 (B,H,N,64)   [0, 4M)        8M halfs   (normed+roped by gemm)
//   kpre f16 (B,H,N,64)   [4M, 8M)
//   vT   f16 (B,H,64,N)   [8M, 12M)      transposed per head
//   xb   bf16 [12M,16M)   (reused as ob after QKV gemm)
//   wqT  bf16 [16M,17.5M) ; woT bf16 [17.5M,18M)
// total 72 MB
#define QSZ 8388608  // halfs per q/k/v region

typedef short bf16x8 __attribute__((ext_vector_type(8)));
typedef _Float16 f16x8 __attribute__((ext_vector_type(8)));
typedef _Float16 f16x4 __attribute__((ext_vector_type(4)));
typedef float f32x4 __attribute__((ext_vector_type(4)));

__device__ __forceinline__ unsigned short f2bf(float f) {
  __hip_bfloat16 h = __float2bfloat16(f);
  return *reinterpret_cast<unsigned short*>(&h);
}

__device__ __forceinline__ void gload16(const void* g, void* l) {
  __builtin_amdgcn_global_load_lds(
      (const __attribute__((address_space(1))) void*)g,
      (__attribute__((address_space(3))) void*)l, 16, 0, 0);
}

// ---------------------------------------------------------------------------
// merged conversion pass (one dispatch, 8192 blocks):
//   [0,4096)     x fp32 -> xb bf16 (elementwise)
//   [4096,7168)  Wqkv [1024,3072] fp32 -> wqT [3072,1024] bf16 (transpose)
//   [7168,8192)  Wout [1024,1024] fp32 -> woT [1024,1024] bf16 (transpose)
// ---------------------------------------------------------------------------
__global__ __launch_bounds__(256)
void cvt_all(const float* __restrict__ x, unsigned short* __restrict__ xb,
             const float* __restrict__ Wq, unsigned short* __restrict__ wqT,
             const float* __restrict__ Wo, unsigned short* __restrict__ woT) {
  __shared__ unsigned short tile[32][33];
  const int bid = blockIdx.x;
  const int t = threadIdx.x;
  if (bid < 4096) {
    const int i = (bid * 256 + t) * 8;
    const float4 a = *(const float4*)&x[i];
    const float4 b = *(const float4*)&x[i + 4];
    ushort4 lo, hi;
    lo.x = f2bf(a.x); lo.y = f2bf(a.y); lo.z = f2bf(a.z); lo.w = f2bf(a.w);
    hi.x = f2bf(b.x); hi.y = f2bf(b.y); hi.z = f2bf(b.z); hi.w = f2bf(b.w);
    *(ushort4*)&xb[i] = lo;
    *(ushort4*)&xb[i + 4] = hi;
    return;
  }
  const float* src;
  unsigned short* dst;
  int bx, by, N;
  if (bid < 7168) {
    src = Wq; dst = wqT; N = 3072;
    bx = (bid - 4096) % 96; by = (bid - 4096) / 96;
  } else {
    src = Wo; dst = woT; N = 1024;
    bx = (bid - 7168) % 32; by = (bid - 7168) / 32;
  }
  const int k0 = by * 32, n0 = bx * 32;
  const int r = t >> 3, c4 = (t & 7) * 4;
  const float4 v = *(const float4*)&src[(k0 + r) * N + n0 + c4];
  tile[r][c4 + 0] = f2bf(v.x);
  tile[r][c4 + 1] = f2bf(v.y);
  tile[r][c4 + 2] = f2bf(v.z);
  tile[r][c4 + 3] = f2bf(v.w);
  __syncthreads();
  ushort4 o;
  o.x = tile[c4 + 0][r];
  o.y = tile[c4 + 1][r];
  o.z = tile[c4 + 2][r];
  o.w = tile[c4 + 3][r];
  *(ushort4*)&dst[(long)(n0 + r) * 1024 + k0 + c4] = o;
}

// ---------------------------------------------------------------------------
// Ring-3 single-barrier counted-vmcnt bf16 GEMM, BK=32:
//   - 512 threads = 8 waves (2M x 4N); bounds (512,2) mandatory ((512,4)
//     spills the unified-file accumulator -- R6 lesson).
//   - LDS: 3-slot ring of BK=32 K-tiles (A+B). Ring safety: tile kt+2's
//     slot was last read at tile kt-1, whose end barrier has passed ->
//     staging is issued MID-COMPUTE of tile kt with NO lgkm-drain barrier.
//     One barrier + one counted vmcnt per tile (vs 2 barriers before).
//   - 64-B rows, 2-bit parity XOR swizzle: phys chunk = logical^((row>>1)&3)
//     (bank = (16r+4c)%32; parity splits halves, XOR cycles within) --
//     conflict-verified at 184K (R4). Inverse-swizzle on the global source.
//   - steady-state wait vmcnt(LPT): retires tile kt+1's loads, leaves tile
//     kt+2's (issued this tile) in flight. Never drains to 0 mid-loop.
// MODE 0 (QKV): BM=256, grid 384 = 32bm x 12bn. Fused RMSNorm + 2D-RoPE
//   epilogue; q/k f16 (B,H,N,64), v f16 transposed. Wave col-span = 1 head.
//   q pre-scaled by hd^-0.5 * log2(e) so attention softmax is a bare exp2.
// MODE 1 (out-proj): BM=128, grid 256 = 64bm x 4bn (one full round).
// XCD map: bm-fastest inside each XCD chunk -> concurrent B-panel window
// fits the 4 MiB XCD L2 (was 6 MB with bn-fastest).
// ---------------------------------------------------------------------------
template<int MODE>
__global__ __launch_bounds__(512, 2)
void gemm256(const unsigned short* __restrict__ A,
             const unsigned short* __restrict__ Bt,
             const float* __restrict__ bias,
             float* __restrict__ Cf,
             __half* __restrict__ Ch,
             const float* __restrict__ qsc,
             const float* __restrict__ ksc) {
  constexpr int BM  = (MODE == 0) ? 256 : 128;  // M-tile
  constexpr int AM  = (MODE == 0) ? 8 : 4;      // acc rows (per-wave M/16)
  constexpr int NT  = 32;                       // K-tiles (K=1024, BK=32)

  __shared__ __align__(16) unsigned short As[3][BM * 32];
  __shared__ __align__(16) unsigned short Bs[3][8192];
  __shared__ float2 Tab[512];  // [pos 0..31][idx 0..15] cos/sin (MODE 0)

  const int t = threadIdx.x;
  // bijective XCD swizzle (nwg % 8 == 0), bm-fastest within an XCD chunk
  const int xcd = blockIdx.x & 7, c = blockIdx.x >> 3;
  int bm, bn;
  if (MODE == 0) { bm = xcd * 4 + (c & 3); bn = c >> 2; }   // 48 blocks/XCD
  else           { bm = xcd * 8 + (c & 7); bn = c >> 3; }   // 32 blocks/XCD
  const int w = t >> 6, lane = t & 63;
  const int M0 = (w >> 2) * (BM / 2), N0 = (w & 3) * 64;
  const int lm = lane & 15, q4 = lane >> 4;

  if (MODE == 0) {  // RoPE table (cross-wave visibility via loop barriers)
    const int pos = t >> 4, idx = t & 15;
    const float invf = expf(-(float)idx * 0.57564627324851149f);
    const float ang = (float)pos * invf;
    Tab[t] = make_float2(cosf(ang), sinf(ang));
  }

  // staging: thread t covers rows (t>>2) [and +128 for BM=256], phys chunk
  // t&3 (lane-linear dest). inverse swizzle on the global source:
  //   logical = (t&3) ^ ((row>>1)&3) = (t&3) ^ ((t>>3)&3)
  // (row+128 gives the same XOR term since (128>>1)&3 == 0).
  const int c8 = (((t & 3) ^ ((t >> 3) & 3)) << 3);
  const unsigned short* aSrc = A + (long)(bm * BM + (t >> 2)) * 1024 + c8;
  const unsigned short* bSrc = Bt + (long)(bn * 256 + (t >> 2)) * 1024 + c8;

  f32x4 acc[AM][4] = {};

  auto stage = [&](int buf, int kt) {  // LPT gload_lds per thread = 1 K-tile
    const unsigned short* a = aSrc + kt * 32;
    const unsigned short* b = bSrc + kt * 32;
    gload16(a, &As[buf][t * 8]);
    if (MODE == 0) gload16(a + 128 * 1024, &As[buf][4096 + t * 8]);
    gload16(b, &Bs[buf][t * 8]);
    gload16(b + 128 * 1024, &Bs[buf][4096 + t * 8]);
  };
  auto waitTile = [] {  // leave exactly one staged tile in flight
    if constexpr (MODE == 0)
      asm volatile("s_waitcnt vmcnt(4)" ::: "memory");
    else
      asm volatile("s_waitcnt vmcnt(3)" ::: "memory");
  };

  // prologue: tiles 0,1 in flight; retire tile 0 (leave tile 1)
  stage(0, 0);
  stage(1, 1);
  waitTile();
  __builtin_amdgcn_s_barrier();

  // steady state: read frags of tile kt from slot kt%3; issue tile kt+2
  // into slot (kt+2)%3 (ring-safe: last read at kt-1, barrier passed);
  // MFMA; vmcnt retires tile kt+1; one barrier.
  for (int kt = 0; kt < NT; ++kt) {
    const unsigned short* Ac = &As[kt % 3][0];
    const unsigned short* Bc = &Bs[kt % 3][0];
    bf16x8 af[AM], bg[4];
#pragma unroll
    for (int mi = 0; mi < AM; ++mi) {
      const int row = M0 + mi * 16 + lm;
      af[mi] = *(const bf16x8*)
          &Ac[row * 32 + ((q4 ^ ((row >> 1) & 3)) << 3)];
    }
#pragma unroll
    for (int ni = 0; ni < 4; ++ni) {
      const int row = N0 + ni * 16 + lm;
      bg[ni] = *(const bf16x8*)
          &Bc[row * 32 + ((q4 ^ ((row >> 1) & 3)) << 3)];
    }
    if (kt < NT - 2) stage((kt + 2) % 3, kt + 2);  // issue hides under MFMA
#pragma unroll
    for (int mi = 0; mi < AM; ++mi)
#pragma unroll
      for (int ni = 0; ni < 4; ++ni)
        acc[mi][ni] = __builtin_amdgcn_mfma_f32_16x16x32_bf16(
            af[mi], bg[ni], acc[mi][ni], 0, 0, 0);
    if (kt < NT - 2) {
      waitTile();                       // retire tile kt+1
      __builtin_amdgcn_s_barrier();
    } else if (kt == NT - 2) {
      asm volatile("s_waitcnt vmcnt(0)" ::: "memory");  // drain last tile
      __builtin_amdgcn_s_barrier();
    }
  }

  // ---- epilogues ----
  const int r0 = q4 << 2;
  const int nb = bn * 256 + N0;

  if (MODE == 1) {  // out-proj: fp32 row-major + bias
#pragma unroll
    for (int mi = 0; mi < AM; ++mi)
#pragma unroll
      for (int ni = 0; ni < 4; ++ni) {
        const int n = nb + ni * 16 + lm;
        const float bvv = bias[n];
#pragma unroll
        for (int r = 0; r < 4; ++r)
          Cf[(long)(bm * BM + M0 + mi * 16 + r0 + r) * 1024 + n] =
              acc[mi][ni][r] + bvv;
      }
    return;
  }

  // MODE 0 fused epilogue (wave col-span = one head)
  const int tq = nb >> 10, h = (nb >> 6) & 15;

  if (tq == 2) {  // v: f16 transpose-scatter (B,H,64,N)
#pragma unroll
    for (int mi = 0; mi < AM; ++mi)
#pragma unroll
      for (int ni = 0; ni < 4; ++ni) {
        const int col = nb + ni * 16 + lm;
        const int dd = col & 63;
        const float bv = bias[col];
#pragma unroll
        for (int r = 0; r < 4; ++r) {
          const int m = bm * BM + M0 + mi * 16 + r0 + r;
          const int b = m >> 10, nn = m & 1023;
          Ch[2L * QSZ + ((long)((b * 16 + h) * 64 + dd)) * 1024 + nn] =
              __float2half(acc[mi][ni][r] + bv);
        }
      }
    return;
  }

  // q or k: RMSNorm + RoPE on f32 accs, then f16 store (B,H,N,64)
  const float* scp = (tq == 0) ? qsc : ksc;
  // q: fold hd^-0.5 AND log2(e) (softmax uses exp2) into the stored q
  const float qmul = (tq == 0) ? 0.18033688011112042f : 1.0f;
  float scv[4], bv[4];
#pragma unroll
  for (int ni = 0; ni < 4; ++ni) {
    scv[ni] = scp[ni * 16 + lm];
    bv[ni] = bias[nb + ni * 16 + lm];
  }
  __half* base = Ch + (long)tq * QSZ;
#pragma unroll
  for (int mi = 0; mi < AM; ++mi) {
#pragma unroll
    for (int r = 0; r < 4; ++r) {
      const float v0 = acc[mi][0][r] + bv[0];
      const float v1 = acc[mi][1][r] + bv[1];
      const float v2 = acc[mi][2][r] + bv[2];
      const float v3 = acc[mi][3][r] + bv[3];
      float ss = v0 * v0 + v1 * v1 + v2 * v2 + v3 * v3;
      ss += __shfl_xor(ss, 1, 64);
      ss += __shfl_xor(ss, 2, 64);
      ss += __shfl_xor(ss, 4, 64);
      ss += __shfl_xor(ss, 8, 64);
      const float inv = rsqrtf(ss * (1.0f / 64.0f) + 1e-6f) * qmul;
      const float a0 = v0 * inv * scv[0];
      const float a1 = v1 * inv * scv[1];
      const float a2 = v2 * inv * scv[2];
      const float a3 = v3 * inv * scv[3];
      const int m = bm * BM + M0 + mi * 16 + r0 + r;
      const int b = m >> 10, nn = m & 1023;
      const float2 tr = Tab[(nn >> 5) * 16 + lm];  // row-part angles
      const float2 tc = Tab[(nn & 31) * 16 + lm];  // col-part angles
      __half* row = base + ((long)((b * 16 + h) * 1024 + nn)) * 64 + lm;
      row[0]  = __float2half(a0 * tr.x - a2 * tr.y);
      row[16] = __float2half(a1 * tc.x - a3 * tc.y);
      row[32] = __float2half(a0 * tr.y + a2 * tr.x);
      row[48] = __float2half(a1 * tc.y + a3 * tc.x);
    }
  }
}

// ---------------------------------------------------------------------------
// MFMA flash attention (f16), fixed-offset softmax (exp2; log2e folded into
// q), single-barrier dbuf, 128 Q-rows per block. K/V fragments hoisted
// (shared by both 16-row groups). QK^T computed SWAPPED -- mfma(K,Q) = S^T:
// each lane holds 4 consecutive k-cols for one q-row (= lm), so the P spill
// is 8x ds_write_b64, l is one scalar per lane (shfl_xor 16|32 reduce).
// ---------------------------------------------------------------------------
__global__ __launch_bounds__(256, 3)
void attn_mfma(const __half* __restrict__ qh, const __half* __restrict__ kh,
               const __half* __restrict__ vh, unsigned short* __restrict__ ob) {
  __shared__ __align__(16) __half Ks[2][4096];  // [krow][d] 64x64, swizzled
  __shared__ __align__(16) __half Vs[2][4096];  // [d][krow] 64x64, swizzled
  __shared__ __align__(16) __half Pl[8][1152];  // [wave*2+g][16 x 72]
  const int t = threadIdx.x;
  const int w = t >> 6, lane = t & 63;
  const int flat = blockIdx.x + blockIdx.y * 8;  // grid (8, 128)
  const int xcd = flat & 7, j = flat >> 3;       // j in [0,128)
  const int bh = xcd * 16 + (j >> 3);            // 16 heads per XCD
  const int qt = j & 7;                          // 128-row Q tile
  const int lm = lane & 15, q4 = lane >> 4;

  f16x8 qf[2][2];
#pragma unroll
  for (int g = 0; g < 2; ++g) {
    const __half* qrow =
        qh + ((long)(bh * 1024 + qt * 128 + g * 64 + w * 16 + lm)) * 64 +
        q4 * 8;
    qf[g][0] = *(const f16x8*)qrow;
    qf[g][1] = *(const f16x8*)(qrow + 32);
  }

  f32x4 o[2][4] = {};
  float l_r[2] = {};

  const int prow = t >> 3, pc = t & 7;
  const int scz = pc ^ (prow & 7);  // swizzled source chunk
  const __half* ksrc0 = kh + (long)(bh * 1024 + prow) * 64 + scz * 8;
  const __half* vsrc0 = vh + (long)(bh * 64 + prow) * 1024 + scz * 8;

  gload16(ksrc0, &Ks[0][t * 8]);
  gload16(ksrc0 + 32 * 64, &Ks[0][2048 + t * 8]);
  gload16(vsrc0, &Vs[0][t * 8]);
  gload16(vsrc0 + 32 * 1024, &Vs[0][2048 + t * 8]);

  for (int kc = 0; kc < 16; ++kc) {
    const int cur = kc & 1;
    __syncthreads();

    if (kc < 15) {
      const int nx = cur ^ 1;
      const __half* ksrc = ksrc0 + (kc + 1) * 4096;
      const __half* vsrc = vsrc0 + (kc + 1) * 64;
      gload16(ksrc, &Ks[nx][t * 8]);
      gload16(ksrc + 32 * 64, &Ks[nx][2048 + t * 8]);
      gload16(vsrc, &Vs[nx][t * 8]);
      gload16(vsrc + 32 * 1024, &Vs[nx][2048 + t * 8]);
    }

    // K fragments once per chunk, shared by both groups
    f16x8 kf[4][2];
#pragma unroll
    for (int nt = 0; nt < 4; ++nt) {
      const int kr = nt * 16 + lm;
#pragma unroll
      for (int ks = 0; ks < 2; ++ks)
        kf[nt][ks] = *(const f16x8*)&Ks[cur][kr * 64 +
                                      (((ks << 2) + q4) ^ (kr & 7)) * 8];
    }

    // S^T = K Q^T per group (lane: q-row = lm, k-cols = nt*16 + q4*4 + r)
#pragma unroll
    for (int g = 0; g < 2; ++g) {
      f32x4 s[4];
      __builtin_amdgcn_s_setprio(1);
#pragma unroll
      for (int nt = 0; nt < 4; ++nt) {
        s[nt] = (f32x4){0.f, 0.f, 0.f, 0.f};
#pragma unroll
        for (int ks = 0; ks < 2; ++ks)
          s[nt] = __builtin_amdgcn_mfma_f32_16x16x32_f16(kf[nt][ks], qf[g][ks],
                                                         s[nt], 0, 0, 0);
      }
      __builtin_amdgcn_s_setprio(0);
      __half* Pw = &Pl[w * 2 + g][0];
      float lacc = 0.f;
#pragma unroll
      for (int nt = 0; nt < 4; ++nt) {
        const float p0 = exp2f(s[nt][0] - 12.98425536800067f);  // 9*log2(e)
        const float p1 = exp2f(s[nt][1] - 12.98425536800067f);
        const float p2 = exp2f(s[nt][2] - 12.98425536800067f);
        const float p3 = exp2f(s[nt][3] - 12.98425536800067f);
        lacc += (p0 + p1) + (p2 + p3);
        f16x4 pv;
        pv[0] = (_Float16)p0; pv[1] = (_Float16)p1;
        pv[2] = (_Float16)p2; pv[3] = (_Float16)p3;
        *(f16x4*)&Pw[lm * 72 + nt * 16 + q4 * 4] = pv;  // one b64 write
      }
      l_r[g] += lacc;
    }

    // O += P V: V fragment read once, feeds both groups
    __builtin_amdgcn_s_setprio(1);
#pragma unroll
    for (int ks2 = 0; ks2 < 2; ++ks2) {
      const f16x8 pf0 = *(const f16x8*)&Pl[w * 2 + 0][lm * 72 + ks2 * 32 +
                                                      q4 * 8];
      const f16x8 pf1 = *(const f16x8*)&Pl[w * 2 + 1][lm * 72 + ks2 * 32 +
                                                      q4 * 8];
#pragma unroll
      for (int nt = 0; nt < 4; ++nt) {
        const int dr = nt * 16 + lm;
        const f16x8 vf = *(const f16x8*)&Vs[cur][dr * 64 +
                                          (((ks2 << 2) + q4) ^ (dr & 7)) * 8];
        o[0][nt] = __builtin_amdgcn_mfma_f32_16x16x32_f16(pf0, vf, o[0][nt],
                                                          0, 0, 0);
        o[1][nt] = __builtin_amdgcn_mfma_f32_16x16x32_f16(pf1, vf, o[1][nt],
                                                          0, 0, 0);
      }
    }
    __builtin_amdgcn_s_setprio(0);
  }

  const int b = bh >> 4, h = bh & 15;
#pragma unroll
  for (int g = 0; g < 2; ++g) {
    float l = l_r[g];                 // partial row-sum, q-row = lm
    l += __shfl_xor(l, 16, 64);       // sum across the 4 q4-lane groups
    l += __shfl_xor(l, 32, 64);
    const float linv_row = 1.0f / l;  // valid at every lane for q-row = lm
#pragma unroll
    for (int r = 0; r < 4; ++r) {
      const float linv = __shfl(linv_row, q4 * 4 + r, 64);  // O-row's qrow
      const long rowg =
          (long)(b * 1024 + qt * 128 + g * 64 + w * 16 + q4 * 4 + r) * 1024 +
          h * 64;
#pragma unroll
      for (int nt = 0; nt < 4; ++nt)
        ob[rowg + nt * 16 + lm] = f2bf(o[g][nt][r] * linv);
    }
  }
}

extern "C" void kernel_launch(void* const* d_in, const int* in_sizes, int n_in,
                              void* d_out, int out_size, void* d_ws,
                              size_t ws_size, hipStream_t stream) {
  const float* x    = (const float*)d_in[0];
  const float* Wqkv = (const float*)d_in[1];
  const float* bqkv = (const float*)d_in[2];
  const float* Wout = (const float*)d_in[3];
  const float* bout = (const float*)d_in[4];
  const float* qs   = (const float*)d_in[5];
  const float* ks   = (const float*)d_in[6];
  float* out = (float*)d_out;
  float* W = (float*)d_ws;  // 72 MB

  __half* qkvh = (__half*)W;            // q:0  k:+QSZ  vT:+2*QSZ (halfs)
  __half* qpre = qkvh;
  __half* kpre = qkvh + QSZ;
  __half* vT   = qkvh + 2 * QSZ;
  unsigned short* xb  = (unsigned short*)(W + 12582912);
  unsigned short* ob  = xb;
  unsigned short* wqT = (unsigned short*)(W + 16777216);
  unsigned short* woT = wqT + 3 * 1024 * 1024;

  // 0) all input conversions in one dispatch
  cvt_all<<<8192, 256, 0, stream>>>(x, xb, Wqkv, wqT, Wout, woT);
  // 1) QKV projection + fused RMSNorm/RoPE (ring-3 single-barrier pipeline)
  gemm256<0><<<384, 512, 0, stream>>>(xb, wqT, bqkv, nullptr, qkvh, qs, ks);
  // 2) MFMA flash attention (128-row blocks) -> ob bf16 row-major
  attn_mfma<<<dim3(8, 128), 256, 0, stream>>>(qpre, kpre, vT, ob);
  // 3) output projection (128x256 tiles; grid 256 = one full round)
  gemm256<1><<<256, 512, 0, stream>>>(ob, woT, bout, out, nullptr, nullptr,
                                      nullptr);
}